// Round 8
// baseline (343.190 us; speedup 1.0000x reference)
//
#include <hip/hip_runtime.h>
#include <math.h>

typedef __attribute__((ext_vector_type(8))) short short8;
typedef __attribute__((ext_vector_type(4))) float f32x4;

__device__ __forceinline__ unsigned f2bf(float f) {
  unsigned u = __float_as_uint(f);
  return (u + 0x7FFFu + ((u >> 16) & 1u)) >> 16;
}
__device__ __forceinline__ unsigned pk2(float lo, float hi) {
  return f2bf(lo) | (f2bf(hi) << 16);
}
__device__ __forceinline__ float bf_lo(unsigned u) { return __uint_as_float(u << 16); }
__device__ __forceinline__ float bf_hi(unsigned u) { return __uint_as_float(u & 0xFFFF0000u); }

// ---------------- workspace layout (float offsets) ----------------
#define WS_X1    0                    // 16384*200
#define WS_W2T   3328000              // 1024*1600 ushorts (bf16) [n][c*40+o]
#define WS_AS    4966400              // 1024
#define WS_AD    4967424              // 1024
#define WS_WEFF  4968464              // 40*30
#define WS_S1    4969664              // 40
#define WS_SH1   4969704              // 40
#define WS_S2    4969744              // 40
#define WS_SH2   4969784              // 40
#define WS_H     4970496              // 1024*256
#define WS_P     5232640              // 1024*1024 normalized softmax P
#define WS_AP    6281216              // 8*1024*256 attention split-K partials
#define WS_Y3P   WS_P                 // 16*64*1400 (overlays P+AP head; dead by k3)
#define WS_Y4    8378368              // 16*1400
#define WS_Y5    8400768              // 16*1400
#define WS_ZP    8455936              // 7*16*1024
#define WS_Z2P   8570624              // 8*16*1024
#define WS_WPT   8701696              // 256*224 bf16: gat_W^T zero-padded
// end 8,730,368 floats = 34.9 MB (< 36.7 MB proven)

// ---------------- k0: param prep + wpadT bf16 + w2t transpose (bf16) ----------------
__global__ __launch_bounds__(256) void k0_prep(const float* __restrict__ gat_W,
                        const float* __restrict__ conv1_w, const float* __restrict__ conv1_b,
                        const float* __restrict__ bn1_g, const float* __restrict__ bn1_b,
                        const float* __restrict__ bn1_m, const float* __restrict__ bn1_v,
                        const float* __restrict__ conv2_b,
                        const float* __restrict__ bn2_g, const float* __restrict__ bn2_b,
                        const float* __restrict__ bn2_m, const float* __restrict__ bn2_v,
                        const float* __restrict__ w2,
                        float* __restrict__ ws) {
  int bx = blockIdx.x, t = threadIdx.x;
  if (bx < 224) {
    unsigned short* wpt = (unsigned short*)(ws + WS_WPT);
    int idx = bx * 256 + t;  // n*224 + k
    int n = idx / 224, k = idx % 224;
    float v = (n < 200 && k < 200) ? gat_W[k * 200 + n] : 0.f;
    wpt[idx] = (unsigned short)f2bf(v);
    return;
  }
  if (bx == 224) {
    if (t < 40) {
      float* weff = ws + WS_WEFF;
      for (int j = 0; j < 30; ++j) {
        float s = 0.f;
        for (int tt = 0; tt < 5; ++tt) {
          int k = j - tt;
          if (k >= 0 && k < 26) s += conv1_w[t * 26 + k];
        }
        weff[t * 30 + j] = s * 0.2f;
      }
      float s1 = bn1_g[t] * rsqrtf(bn1_v[t] + 1e-5f);
      ws[WS_S1 + t] = s1;
      ws[WS_SH1 + t] = bn1_b[t] + (conv1_b[t] - bn1_m[t]) * s1;
      float s2 = bn2_g[t] * rsqrtf(bn2_v[t] + 1e-5f);
      ws[WS_S2 + t] = s2;
      ws[WS_SH2 + t] = bn2_b[t] + (conv2_b[t] - bn2_m[t]) * s2;
    }
    return;
  }
  __shared__ float tile[32][65];
  int q = bx - 225;
  int jt = (q / 16) * 32;
  int n0 = (q % 16) * 64;
  unsigned short* w2t = (unsigned short*)(ws + WS_W2T);
  for (int i = t; i < 2048; i += 256) {
    int jr = i >> 6, n = i & 63;
    int j = jt + jr;
    int o = j % 40, c = j / 40;
    tile[jr][n] = w2[(o * 40 + c) * 1024 + n0 + n];
  }
  __syncthreads();
  for (int i = t; i < 2048; i += 256) {
    int nr = i >> 5, j = i & 31;
    w2t[(n0 + nr) * 1600 + jt + j] = (unsigned short)f2bf(tile[j][nr]);
  }
}

// ---------------- k1: MFMA bf16 GEMM h = x @ W (K=200 pad 224) ----------------
__global__ __launch_bounds__(256) void k1_mfma(const float* __restrict__ x,
                                               const unsigned short* __restrict__ wpt,
                                               const float* __restrict__ gat_b,
                                               float* __restrict__ h,
                                               float* __restrict__ x1) {
  __shared__ unsigned short Bt[64 * 232];    // [n][k] bf16, stride 232
  __shared__ unsigned short As[2][64 * 40];  // [m][k32] bf16, stride 40
  int t = threadIdx.x;
  int wave = t >> 6, lane = t & 63;
  int m16 = lane & 15, quad = lane >> 4;
  int row0 = blockIdx.x * 64, n0 = blockIdx.y * 64;
  for (int i = t; i < 1792; i += 256) {
    int row = i / 28, ch = i % 28;
    *(short8*)&Bt[row * 232 + ch * 8] = *(const short8*)&wpt[(n0 + row) * 224 + ch * 8];
  }
  {
    int m = t >> 2, kq = (t & 3) * 8;
    const float* xr = x + (row0 + m) * 200 + kq;
    float4 a = *(const float4*)xr;
    float4 b = *(const float4*)(xr + 4);
    uint4 pv;
    pv.x = pk2(a.x, a.y); pv.y = pk2(a.z, a.w);
    pv.z = pk2(b.x, b.y); pv.w = pk2(b.z, b.w);
    *(uint4*)&As[0][m * 40 + kq] = pv;
  }
  __syncthreads();
  f32x4 acc0 = {0.f, 0.f, 0.f, 0.f}, acc1 = acc0, acc2 = acc0, acc3 = acc0;
  int buf = 0;
  for (int s = 0; s < 7; ++s) {
    if (s < 6) {
      int m = t >> 2, kq = (t & 3) * 8;
      int kg = (s + 1) * 32 + kq;
      const float* xr = x + (row0 + m) * 200;
      uint4 pv;
      if (kg + 8 <= 200) {
        float4 a = *(const float4*)(xr + kg);
        float4 b = *(const float4*)(xr + kg + 4);
        pv.x = pk2(a.x, a.y); pv.y = pk2(a.z, a.w);
        pv.z = pk2(b.x, b.y); pv.w = pk2(b.z, b.w);
      } else {
        float e[8];
#pragma unroll
        for (int q = 0; q < 8; ++q) e[q] = (kg + q < 200) ? xr[kg + q] : 0.f;
        pv.x = pk2(e[0], e[1]); pv.y = pk2(e[2], e[3]);
        pv.z = pk2(e[4], e[5]); pv.w = pk2(e[6], e[7]);
      }
      *(uint4*)&As[buf ^ 1][m * 40 + kq] = pv;
    }
    short8 af = *(const short8*)&As[buf][(wave * 16 + m16) * 40 + quad * 8];
    int kb = s * 32 + quad * 8;
    short8 b0 = *(const short8*)&Bt[(0 * 16 + m16) * 232 + kb];
    short8 b1 = *(const short8*)&Bt[(1 * 16 + m16) * 232 + kb];
    short8 b2 = *(const short8*)&Bt[(2 * 16 + m16) * 232 + kb];
    short8 b3 = *(const short8*)&Bt[(3 * 16 + m16) * 232 + kb];
    acc0 = __builtin_amdgcn_mfma_f32_16x16x32_bf16(af, b0, acc0, 0, 0, 0);
    acc1 = __builtin_amdgcn_mfma_f32_16x16x32_bf16(af, b1, acc1, 0, 0, 0);
    acc2 = __builtin_amdgcn_mfma_f32_16x16x32_bf16(af, b2, acc2, 0, 0, 0);
    acc3 = __builtin_amdgcn_mfma_f32_16x16x32_bf16(af, b3, acc3, 0, 0, 0);
    __syncthreads();
    buf ^= 1;
  }
  f32x4 accs[4] = {acc0, acc1, acc2, acc3};
  if (blockIdx.x < 16) {
#pragma unroll
    for (int nt = 0; nt < 4; ++nt)
#pragma unroll
      for (int r = 0; r < 4; ++r) {
        int row = row0 + wave * 16 + quad * 4 + r;
        h[row * 256 + n0 + nt * 16 + m16] = accs[nt][r];
      }
  } else {
#pragma unroll
    for (int nt = 0; nt < 4; ++nt) {
      int col = n0 + nt * 16 + m16;
      if (col < 200) {
#pragma unroll
        for (int r = 0; r < 4; ++r) {
          int row = row0 + wave * 16 + quad * 4 + r;
          x1[row * 200 + col] = x[row * 200 + col] + accs[nt][r] + gat_b[col];
        }
      }
    }
  }
}

// ---------------- k1b: attention scores ----------------
__global__ void k1b_scores(const float* __restrict__ h, const float* __restrict__ att_src,
                           const float* __restrict__ att_dst, float* __restrict__ as_,
                           float* __restrict__ ad_) {
  int r = blockIdx.x * 256 + threadIdx.x;
  const float* hr = h + r * 256;
  float s = 0.f, d = 0.f;
  for (int f = 0; f < 200; ++f) {
    float v = hr[f];
    s += v * att_src[f];
    d += v * att_dst[f];
  }
  as_[r] = s;
  ad_[r] = d;
}

// ---------------- kP: normalized softmax P (max computed inline) ----------------
__global__ __launch_bounds__(256) void kP(const float* __restrict__ as_,
                                          const float* __restrict__ ad_,
                                          float* __restrict__ P) {
  __shared__ float rb[256];
  int t = threadIdx.x, i = blockIdx.x;
  float a0 = as_[t], a1 = as_[256 + t], a2 = as_[512 + t], a3 = as_[768 + t];
  rb[t] = fmaxf(fmaxf(a0, a1), fmaxf(a2, a3));
  __syncthreads();
  for (int st = 128; st > 0; st >>= 1) {
    if (t < st) rb[t] = fmaxf(rb[t], rb[t + st]);
    __syncthreads();
  }
  float maxs = rb[0];
  __syncthreads();
  float ad = ad_[i];
  float mv = maxs + ad;
  float M = mv >= 0.f ? mv : 0.2f * mv;
  float av[4] = {a0, a1, a2, a3};
  float p[4];
  float s = 0.f;
#pragma unroll
  for (int q = 0; q < 4; ++q) {
    float v = av[q] + ad;
    float l = v >= 0.f ? v : 0.2f * v;
    p[q] = __expf(l - M);
    s += p[q];
  }
  rb[t] = s;
  __syncthreads();
  for (int st = 128; st > 0; st >>= 1) {
    if (t < st) rb[t] += rb[t + st];
    __syncthreads();
  }
  float inv = 1.f / rb[0];
#pragma unroll
  for (int q = 0; q < 4; ++q) P[i * 1024 + q * 256 + t] = p[q] * inv;
}

// ---------------- kAttn: split-K GEMM out0 = P @ h (8 K-chunks) ----------------
__global__ __launch_bounds__(256) void kAttn(const float* __restrict__ P,
                                             const float* __restrict__ h,
                                             float* __restrict__ ap) {
  __shared__ __align__(16) float As2[8][64];
  __shared__ __align__(16) float Bs[8][64];
  int t = threadIdx.x;
  int tm = t & 15, tn = t >> 4;
  int i0 = blockIdx.x * 64, f0 = blockIdx.y * 64, j0 = blockIdx.z * 128;
  float acc[4][4] = {};
  for (int k0 = 0; k0 < 128; k0 += 8) {
    for (int i = t; i < 512; i += 256) {
      int m = i >> 3, k = i & 7;
      As2[k][m] = P[(i0 + m) * 1024 + j0 + k0 + k];
    }
    for (int i = t; i < 512; i += 256) {
      int k = i >> 6, n = i & 63;
      Bs[k][n] = h[(j0 + k0 + k) * 256 + f0 + n];
    }
    __syncthreads();
#pragma unroll
    for (int k = 0; k < 8; ++k) {
      float4 a = *(const float4*)&As2[k][tm * 4];
      float4 bq = *(const float4*)&Bs[k][tn * 4];
      float av[4] = {a.x, a.y, a.z, a.w};
      float bv[4] = {bq.x, bq.y, bq.z, bq.w};
#pragma unroll
      for (int i = 0; i < 4; ++i)
#pragma unroll
        for (int j = 0; j < 4; ++j) acc[i][j] += av[i] * bv[j];
    }
    __syncthreads();
  }
#pragma unroll
  for (int i = 0; i < 4; ++i) {
    int r = i0 + tm * 4 + i;
    float4 v = make_float4(acc[i][0], acc[i][1], acc[i][2], acc[i][3]);
    *(float4*)&ap[(blockIdx.z * 1024 + r) * 256 + f0 + tn * 4] = v;
  }
}

// ---------------- kAttnRed ----------------
__global__ __launch_bounds__(256) void kAttnRed(const float* __restrict__ ap,
                                                const float* __restrict__ x,
                                                const float* __restrict__ gat_b,
                                                float* __restrict__ x1) {
  int t = threadIdx.x, r = blockIdx.x;
  if (t >= 200) return;
  float s = 0.f;
#pragma unroll
  for (int z = 0; z < 8; ++z) s += ap[(z * 1024 + r) * 256 + t];
  x1[r * 200 + t] = x[r * 200 + t] + s + gat_b[t];
}

// ---------------- k3: fused conv1+bn1+elu+conv2 v8 ----------------
// grid (16,64), block 320; 4 iters x 4 nodes (16 nodes/block).
// conv1 reads x1 directly from global (L1-hit, 70x reuse) — no xbp LDS.
// w2 staged in LDS as bf16 (12.8 KB). LDS total ~35.9 KB -> 3 blocks/CU
// with VGPR <=~160 under (320,2). Conflicts: only tmpB b128 traffic remains.
__global__ __launch_bounds__(320, 2) void k3_conv(const float* __restrict__ x1,
                                                  const unsigned short* __restrict__ w2t,
                                                  const float* __restrict__ ws,
                                                  float* __restrict__ y3p) {
  __shared__ __align__(16) unsigned short w2s[6400];    // 4 node rows bf16
  __shared__ __align__(16) unsigned short tmpB[11552];  // 4 nodes x (40c x 72 + 8)
  int t = threadIdx.x;
  int b = blockIdx.x, nt = blockIdx.y;
  int base_n = nt * 16;
  int c1 = t / 7, wg = t % 7;
  int nn2 = t / 70, rr = t % 70, cg = rr / 7, pg = rr % 7;
  float wr[30];
  float s1c = 0.f, sh1c = 0.f;
  if (t < 280) {
    const float* weff = ws + WS_WEFF + c1 * 30;
#pragma unroll
    for (int j = 0; j < 30; ++j) wr[j] = weff[j];
    s1c = ws[WS_S1 + c1];
    sh1c = ws[WS_SH1 + c1];
  }
  float acc[4][5] = {};
  for (int it = 0; it < 4; ++it) {
    int n0 = base_n + it * 4;
    // stage w2s (bf16) for 4 nodes
    {
      const short8* wsrc = (const short8*)(w2t + n0 * 1600);
      short8* wdst = (short8*)w2s;
      for (int i = t; i < 800; i += 320) wdst[i] = wsrc[i];
    }
    // conv1 from global x1 + bn1 + elu -> tmpB (bf16)
    if (t < 280) {
#pragma unroll
      for (int nn = 0; nn < 4; ++nn) {
        const float* xr = x1 + (b * 1024 + n0 + nn) * 200 + wg * 25;
        float xw[50];
        __builtin_memcpy(xw, xr, 50 * sizeof(float));
        float e[5];
#pragma unroll
        for (int u = 0; u < 5; ++u) {
          float s = 0.f;
#pragma unroll
          for (int j = 0; j < 30; ++j) s += xw[u * 5 + j] * wr[j];
          float v = s * s1c + sh1c;
          e[u] = v > 0.f ? v : __expf(v) - 1.f;
        }
        uint4 pv;
        pv.x = pk2(e[0], e[1]); pv.y = pk2(e[2], e[3]);
        pv.z = pk2(e[4], 0.f);  pv.w = 0u;
        *(uint4*)&tmpB[nn * 2888 + c1 * 72 + wg * 8] = pv;
      }
    }
    __syncthreads();
    // conv2: tmp (bf16, LDS) x w2 (bf16, LDS)
    if (t < 280) {
      const unsigned short* tb = &tmpB[nn2 * 2888 + pg * 8];
      const unsigned short* wb = &w2s[nn2 * 1600 + cg * 4];
#pragma unroll 4
      for (int cc = 0; cc < 40; ++cc) {
        uint4 tv = *(const uint4*)&tb[cc * 72];
        float t0 = bf_lo(tv.x), t1 = bf_hi(tv.x);
        float t2 = bf_lo(tv.y), t3 = bf_hi(tv.y);
        float t4 = bf_lo(tv.z);
        uint2 wv = *(const uint2*)&wb[cc * 40];
        float w0 = bf_lo(wv.x), w1 = bf_hi(wv.x);
        float w2f = bf_lo(wv.y), w3 = bf_hi(wv.y);
        acc[0][0] += t0 * w0; acc[0][1] += t1 * w0; acc[0][2] += t2 * w0;
        acc[0][3] += t3 * w0; acc[0][4] += t4 * w0;
        acc[1][0] += t0 * w1; acc[1][1] += t1 * w1; acc[1][2] += t2 * w1;
        acc[1][3] += t3 * w1; acc[1][4] += t4 * w1;
        acc[2][0] += t0 * w2f; acc[2][1] += t1 * w2f; acc[2][2] += t2 * w2f;
        acc[2][3] += t3 * w2f; acc[2][4] += t4 * w2f;
        acc[3][0] += t0 * w3; acc[3][1] += t1 * w3; acc[3][2] += t2 * w3;
        acc[3][3] += t3 * w3; acc[3][4] += t4 * w3;
      }
    }
    __syncthreads();
  }
  // cross-nn2 reduction: reuse tmpB as float scratch (5600 floats <= 5776)
  float* red = (float*)tmpB;
  if (t < 280) {
#pragma unroll
    for (int oi = 0; oi < 4; ++oi)
#pragma unroll
      for (int u = 0; u < 5; ++u)
        red[nn2 * 1400 + (cg * 4 + oi) * 35 + pg * 5 + u] = acc[oi][u];
  }
  __syncthreads();
  float* dst = y3p + (b * 64 + nt) * 1400;
  for (int idx = t; idx < 1400; idx += 320)
    dst[idx] = red[idx] + red[1400 + idx] + red[2800 + idx] + red[4200 + idx];
}

// ---------------- k4a: reduce 64 partials + bn2 + elu -> y4 ----------------
__global__ __launch_bounds__(256) void k4a_red(const float* __restrict__ y3p,
                                               const float* __restrict__ ws,
                                               float* __restrict__ y4) {
  int t = threadIdx.x;
  if (t >= 200) return;
  int b = blockIdx.x;
  int idx = blockIdx.y * 200 + t;
  float s = 0.f;
#pragma unroll 4
  for (int q = 0; q < 64; ++q) s += y3p[(b * 64 + q) * 1400 + idx];
  int o = idx / 35;
  float v = s * ws[WS_S2 + o] + ws[WS_SH2 + o];
  y4[b * 1400 + idx] = v > 0.f ? v : __expf(v) - 1.f;
}

// ---------------- k4b: projc + rearrange -> y5 ----------------
__global__ __launch_bounds__(256) void k4b_proj(const float* __restrict__ y4,
                                                const float* __restrict__ projc_w,
                                                const float* __restrict__ projc_b,
                                                float* __restrict__ y5) {
  __shared__ __align__(16) float tls[1400];
  int t = threadIdx.x, b = blockIdx.x;
  for (int i = t; i < 350; i += 256)
    ((float4*)tls)[i] = ((const float4*)(y4 + b * 1400))[i];
  __syncthreads();
  for (int idx = t; idx < 1400; idx += 256) {
    int p = idx / 40, e = idx % 40;
    float acc = projc_b[e];
    for (int o = 0; o < 40; ++o) acc += tls[o * 35 + p] * projc_w[e * 40 + o];
    y5[b * 1400 + idx] = acc;
  }
}

// ---------------- k5: split-K FC1 partials ----------------
__global__ __launch_bounds__(256) void k5_fc1(const float* __restrict__ y5,
                                              const float* __restrict__ W1,
                                              float* __restrict__ zp) {
  __shared__ __align__(16) float yls[3200];
  int t = threadIdx.x;
  int nc = blockIdx.x, kc = blockIdx.y;  // (32, 7)
  for (int i = t; i < 800; i += 256) {
    int bb = i / 50, q = i % 50;
    ((float4*)yls)[bb * 50 + q] = *(const float4*)(y5 + bb * 1400 + kc * 200 + q * 4);
  }
  __syncthreads();
  int nl = t & 31, bg = t >> 5;
  int n = nc * 32 + nl;
  float acc0 = 0.f, acc1 = 0.f;
  const float* y0 = yls + (bg * 2) * 200;
  const float* y1 = yls + (bg * 2 + 1) * 200;
  for (int k = 0; k < 200; ++k) {
    float w = W1[(kc * 200 + k) * 1024 + n];
    acc0 += y0[k] * w;
    acc1 += y1[k] * w;
  }
  zp[(kc * 16 + bg * 2) * 1024 + n] = acc0;
  zp[(kc * 16 + bg * 2 + 1) * 1024 + n] = acc1;
}

// ---------------- k6: split-K FC2 partials, gelu(z) on the fly ----------------
__global__ __launch_bounds__(256) void k6_fc2(const float* __restrict__ zp,
                                              const float* __restrict__ b1,
                                              const float* __restrict__ W2,
                                              float* __restrict__ z2p) {
  __shared__ __align__(16) float gls[2048];
  int t = threadIdx.x;
  int nc = blockIdx.x, kc = blockIdx.y;  // (32, 8)
  for (int i = t; i < 2048; i += 256) {
    int bb = i >> 7, kk = i & 127;
    int np = kc * 128 + kk;
    float s = b1[np];
#pragma unroll
    for (int j = 0; j < 7; ++j) s += zp[(j * 16 + bb) * 1024 + np];
    gls[i] = 0.5f * s * (1.f + erff(s * 0.70710678f));
  }
  __syncthreads();
  int nl = t & 31, bg = t >> 5;
  int n = nc * 32 + nl;
  float acc0 = 0.f, acc1 = 0.f;
  const float* g0 = gls + (bg * 2) * 128;
  const float* g1 = gls + (bg * 2 + 1) * 128;
  for (int k = 0; k < 128; ++k) {
    float w = W2[(kc * 128 + k) * 1024 + n];
    acc0 += g0[k] * w;
    acc1 += g1[k] * w;
  }
  z2p[(kc * 16 + bg * 2) * 1024 + n] = acc0;
  z2p[(kc * 16 + bg * 2 + 1) * 1024 + n] = acc1;
}

// ---------------- k7: z recompute + FC2 reduce + residual + LayerNorm ----------------
__global__ __launch_bounds__(256) void k7_ln(const float* __restrict__ zp,
                                             const float* __restrict__ z2p,
                                             const float* __restrict__ b1,
                                             const float* __restrict__ b2,
                                             const float* __restrict__ ln_g,
                                             const float* __restrict__ ln_b,
                                             float* __restrict__ out) {
  __shared__ float r1[256], r2[256];
  int t = threadIdx.x, b = blockIdx.x;
  float4 v = *(const float4*)(b1 + t * 4);
  float4 bb2 = *(const float4*)(b2 + t * 4);
  v.x += bb2.x; v.y += bb2.y; v.z += bb2.z; v.w += bb2.w;
#pragma unroll
  for (int kc = 0; kc < 7; ++kc) {
    float4 p = *(const float4*)(zp + (kc * 16 + b) * 1024 + t * 4);
    v.x += p.x; v.y += p.y; v.z += p.z; v.w += p.w;
  }
#pragma unroll
  for (int kc = 0; kc < 8; ++kc) {
    float4 p = *(const float4*)(z2p + (kc * 16 + b) * 1024 + t * 4);
    v.x += p.x; v.y += p.y; v.z += p.z; v.w += p.w;
  }
  r1[t] = v.x + v.y + v.z + v.w;
  r2[t] = v.x * v.x + v.y * v.y + v.z * v.z + v.w * v.w;
  __syncthreads();
  for (int s = 128; s > 0; s >>= 1) {
    if (t < s) {
      r1[t] += r1[t + s];
      r2[t] += r2[t + s];
    }
    __syncthreads();
  }
  float mu = r1[0] * (1.f / 1024.f);
  float var = r2[0] * (1.f / 1024.f) - mu * mu;
  float rstd = rsqrtf(var + 1e-5f);
  float4 gg = *(const float4*)(ln_g + t * 4);
  float4 bb = *(const float4*)(ln_b + t * 4);
  float4 o;
  o.x = (v.x - mu) * rstd * gg.x + bb.x;
  o.y = (v.y - mu) * rstd * gg.y + bb.y;
  o.z = (v.z - mu) * rstd * gg.z + bb.z;
  o.w = (v.w - mu) * rstd * gg.w + bb.w;
  *(float4*)(out + b * 1024 + t * 4) = o;
}

extern "C" void kernel_launch(void* const* d_in, const int* in_sizes, int n_in,
                              void* d_out, int out_size, void* d_ws, size_t ws_size,
                              hipStream_t stream) {
  (void)in_sizes; (void)n_in; (void)out_size; (void)ws_size;
  const float* x       = (const float*)d_in[0];
  const float* gat_W   = (const float*)d_in[1];
  const float* att_src = (const float*)d_in[2];
  const float* att_dst = (const float*)d_in[3];
  const float* gat_b   = (const float*)d_in[4];
  const float* conv1_w = (const float*)d_in[5];
  const float* conv2_w = (const float*)d_in[11];
  const float* projc_w = (const float*)d_in[17];
  const float* projc_b = (const float*)d_in[18];
  const float* W1      = (const float*)d_in[19];
  const float* b1      = (const float*)d_in[20];
  const float* W2      = (const float*)d_in[21];
  const float* b2      = (const float*)d_in[22];
  const float* ln_g    = (const float*)d_in[23];
  const float* ln_b    = (const float*)d_in[24];
  float* ws  = (float*)d_ws;
  float* out = (float*)d_out;

  hipLaunchKernelGGL(k0_prep, dim3(1025), dim3(256), 0, stream, gat_W, conv1_w,
                     (const float*)d_in[6], (const float*)d_in[7], (const float*)d_in[8],
                     (const float*)d_in[9], (const float*)d_in[10], (const float*)d_in[12],
                     (const float*)d_in[13], (const float*)d_in[14], (const float*)d_in[15],
                     (const float*)d_in[16], conv2_w, ws);
  hipLaunchKernelGGL(k1_mfma, dim3(256, 4), dim3(256), 0, stream, x,
                     (const unsigned short*)(ws + WS_WPT), gat_b, ws + WS_H, ws + WS_X1);
  hipLaunchKernelGGL(k1b_scores, dim3(4), dim3(256), 0, stream, ws + WS_H, att_src, att_dst,
                     ws + WS_AS, ws + WS_AD);
  hipLaunchKernelGGL(kP, dim3(1024), dim3(256), 0, stream, ws + WS_AS, ws + WS_AD, ws + WS_P);
  hipLaunchKernelGGL(kAttn, dim3(16, 4, 8), dim3(256), 0, stream, ws + WS_P, ws + WS_H,
                     ws + WS_AP);
  hipLaunchKernelGGL(kAttnRed, dim3(1024), dim3(256), 0, stream, ws + WS_AP, x, gat_b,
                     ws + WS_X1);
  hipLaunchKernelGGL(k3_conv, dim3(16, 64), dim3(320), 0, stream, ws + WS_X1,
                     (const unsigned short*)(ws + WS_W2T), ws, ws + WS_Y3P);
  hipLaunchKernelGGL(k4a_red, dim3(16, 7), dim3(256), 0, stream, ws + WS_Y3P, ws, ws + WS_Y4);
  hipLaunchKernelGGL(k4b_proj, dim3(16), dim3(256), 0, stream, ws + WS_Y4, projc_w, projc_b,
                     ws + WS_Y5);
  hipLaunchKernelGGL(k5_fc1, dim3(32, 7), dim3(256), 0, stream, ws + WS_Y5, W1, ws + WS_ZP);
  hipLaunchKernelGGL(k6_fc2, dim3(32, 8), dim3(256), 0, stream, ws + WS_ZP, b1, W2,
                     ws + WS_Z2P);
  hipLaunchKernelGGL(k7_ln, dim3(16), dim3(256), 0, stream, ws + WS_ZP, ws + WS_Z2P, b1, b2,
                     ln_g, ln_b, out);
}

// Round 9
// 280.415 us; speedup vs baseline: 1.2239x; 1.2239x over previous
//
#include <hip/hip_runtime.h>
#include <math.h>

typedef __attribute__((ext_vector_type(8))) short short8;
typedef __attribute__((ext_vector_type(4))) float f32x4;

__device__ __forceinline__ unsigned f2bf(float f) {
  unsigned u = __float_as_uint(f);
  return (u + 0x7FFFu + ((u >> 16) & 1u)) >> 16;
}
__device__ __forceinline__ unsigned pk2(float lo, float hi) {
  return f2bf(lo) | (f2bf(hi) << 16);
}

// ---------------- workspace layout (float offsets) ----------------
#define WS_X1    0                    // 16384*200
#define WS_W2P   3328000              // w2pre: 128*48*320 bf16 shorts = 983040 floats
#define WS_AS    4966400              // 1024
#define WS_AD    4967424              // 1024
#define WS_WEFF  4968464              // 40*30
#define WS_S1    4969664              // 40
#define WS_SH1   4969704              // 40
#define WS_S2    4969744              // 40
#define WS_SH2   4969784              // 40
#define WS_H     4970496              // 1024*256
#define WS_P     5232640              // 1024*1024 normalized softmax P
#define WS_AP    6281216              // 8*1024*256 attention split-K partials
#define WS_Y3P   WS_P                 // 16*128*1400 = 2.87M (overlays P+AP; dead by k3)
#define WS_Y4    8378368              // 16*1400
#define WS_Y5    8400768              // 16*1400
#define WS_ZP    8455936              // 7*16*1024
#define WS_Z2P   8570624              // 8*16*1024
#define WS_WPT   8701696              // 256*224 bf16: gat_W^T zero-padded
// end 8,730,368 floats = 34.9 MB (< 36.7 MB proven)

// ---------------- k0: param prep + wpadT bf16 + w2pre (B-layout bf16) ----------------
__global__ __launch_bounds__(256) void k0_prep(const float* __restrict__ gat_W,
                        const float* __restrict__ conv1_w, const float* __restrict__ conv1_b,
                        const float* __restrict__ bn1_g, const float* __restrict__ bn1_b,
                        const float* __restrict__ bn1_m, const float* __restrict__ bn1_v,
                        const float* __restrict__ conv2_b,
                        const float* __restrict__ bn2_g, const float* __restrict__ bn2_b,
                        const float* __restrict__ bn2_m, const float* __restrict__ bn2_v,
                        const float* __restrict__ w2,
                        float* __restrict__ ws) {
  int bx = blockIdx.x, t = threadIdx.x;
  if (bx < 224) {
    unsigned short* wpt = (unsigned short*)(ws + WS_WPT);
    int idx = bx * 256 + t;  // n*224 + k
    int n = idx / 224, k = idx % 224;
    float v = (n < 200 && k < 200) ? gat_W[k * 200 + n] : 0.f;
    wpt[idx] = (unsigned short)f2bf(v);
    return;
  }
  if (bx == 224) {
    if (t < 40) {
      float* weff = ws + WS_WEFF;
      for (int j = 0; j < 30; ++j) {
        float s = 0.f;
        for (int tt = 0; tt < 5; ++tt) {
          int k = j - tt;
          if (k >= 0 && k < 26) s += conv1_w[t * 26 + k];
        }
        weff[t * 30 + j] = s * 0.2f;
      }
      float s1 = bn1_g[t] * rsqrtf(bn1_v[t] + 1e-5f);
      ws[WS_S1 + t] = s1;
      ws[WS_SH1 + t] = bn1_b[t] + (conv1_b[t] - bn1_m[t]) * s1;
      float s2 = bn2_g[t] * rsqrtf(bn2_v[t] + 1e-5f);
      ws[WS_S2 + t] = s2;
      ws[WS_SH2 + t] = bn2_b[t] + (conv2_b[t] - bn2_m[t]) * s2;
    }
    return;
  }
  // w2pre[(c8*48 + o)*320 + k] = bf16(w2[o][c=k%40][n=c8*8+k/40]), o>=40 -> 0
  int idx = (bx - 225) * 256 + t;  // < 128*48*320 = 1,966,080
  if (idx < 1966080) {
    unsigned short* w2p = (unsigned short*)(ws + WS_W2P);
    int k = idx % 320;
    int rem = idx / 320;
    int o = rem % 48, c8 = rem / 48;
    float v = 0.f;
    if (o < 40) {
      int c = k % 40, nl = k / 40;
      v = w2[(o * 40 + c) * 1024 + c8 * 8 + nl];
    }
    w2p[idx] = (unsigned short)f2bf(v);
  }
}

// ---------------- k1: MFMA bf16 GEMM h = x @ W (K=200 pad 224) ----------------
__global__ __launch_bounds__(256) void k1_mfma(const float* __restrict__ x,
                                               const unsigned short* __restrict__ wpt,
                                               const float* __restrict__ gat_b,
                                               float* __restrict__ h,
                                               float* __restrict__ x1) {
  __shared__ unsigned short Bt[64 * 232];    // [n][k] bf16, stride 232
  __shared__ unsigned short As[2][64 * 40];  // [m][k32] bf16, stride 40
  int t = threadIdx.x;
  int wave = t >> 6, lane = t & 63;
  int m16 = lane & 15, quad = lane >> 4;
  int row0 = blockIdx.x * 64, n0 = blockIdx.y * 64;
  for (int i = t; i < 1792; i += 256) {
    int row = i / 28, ch = i % 28;
    *(short8*)&Bt[row * 232 + ch * 8] = *(const short8*)&wpt[(n0 + row) * 224 + ch * 8];
  }
  {
    int m = t >> 2, kq = (t & 3) * 8;
    const float* xr = x + (row0 + m) * 200 + kq;
    float4 a = *(const float4*)xr;
    float4 b = *(const float4*)(xr + 4);
    uint4 pv;
    pv.x = pk2(a.x, a.y); pv.y = pk2(a.z, a.w);
    pv.z = pk2(b.x, b.y); pv.w = pk2(b.z, b.w);
    *(uint4*)&As[0][m * 40 + kq] = pv;
  }
  __syncthreads();
  f32x4 acc0 = {0.f, 0.f, 0.f, 0.f}, acc1 = acc0, acc2 = acc0, acc3 = acc0;
  int buf = 0;
  for (int s = 0; s < 7; ++s) {
    if (s < 6) {
      int m = t >> 2, kq = (t & 3) * 8;
      int kg = (s + 1) * 32 + kq;
      const float* xr = x + (row0 + m) * 200;
      uint4 pv;
      if (kg + 8 <= 200) {
        float4 a = *(const float4*)(xr + kg);
        float4 b = *(const float4*)(xr + kg + 4);
        pv.x = pk2(a.x, a.y); pv.y = pk2(a.z, a.w);
        pv.z = pk2(b.x, b.y); pv.w = pk2(b.z, b.w);
      } else {
        float e[8];
#pragma unroll
        for (int q = 0; q < 8; ++q) e[q] = (kg + q < 200) ? xr[kg + q] : 0.f;
        pv.x = pk2(e[0], e[1]); pv.y = pk2(e[2], e[3]);
        pv.z = pk2(e[4], e[5]); pv.w = pk2(e[6], e[7]);
      }
      *(uint4*)&As[buf ^ 1][m * 40 + kq] = pv;
    }
    short8 af = *(const short8*)&As[buf][(wave * 16 + m16) * 40 + quad * 8];
    int kb = s * 32 + quad * 8;
    short8 b0 = *(const short8*)&Bt[(0 * 16 + m16) * 232 + kb];
    short8 b1 = *(const short8*)&Bt[(1 * 16 + m16) * 232 + kb];
    short8 b2 = *(const short8*)&Bt[(2 * 16 + m16) * 232 + kb];
    short8 b3 = *(const short8*)&Bt[(3 * 16 + m16) * 232 + kb];
    acc0 = __builtin_amdgcn_mfma_f32_16x16x32_bf16(af, b0, acc0, 0, 0, 0);
    acc1 = __builtin_amdgcn_mfma_f32_16x16x32_bf16(af, b1, acc1, 0, 0, 0);
    acc2 = __builtin_amdgcn_mfma_f32_16x16x32_bf16(af, b2, acc2, 0, 0, 0);
    acc3 = __builtin_amdgcn_mfma_f32_16x16x32_bf16(af, b3, acc3, 0, 0, 0);
    __syncthreads();
    buf ^= 1;
  }
  f32x4 accs[4] = {acc0, acc1, acc2, acc3};
  if (blockIdx.x < 16) {
#pragma unroll
    for (int nt = 0; nt < 4; ++nt)
#pragma unroll
      for (int r = 0; r < 4; ++r) {
        int row = row0 + wave * 16 + quad * 4 + r;
        h[row * 256 + n0 + nt * 16 + m16] = accs[nt][r];
      }
  } else {
#pragma unroll
    for (int nt = 0; nt < 4; ++nt) {
      int col = n0 + nt * 16 + m16;
      if (col < 200) {
#pragma unroll
        for (int r = 0; r < 4; ++r) {
          int row = row0 + wave * 16 + quad * 4 + r;
          x1[row * 200 + col] = x[row * 200 + col] + accs[nt][r] + gat_b[col];
        }
      }
    }
  }
}

// ---------------- k1b: attention scores ----------------
__global__ void k1b_scores(const float* __restrict__ h, const float* __restrict__ att_src,
                           const float* __restrict__ att_dst, float* __restrict__ as_,
                           float* __restrict__ ad_) {
  int r = blockIdx.x * 256 + threadIdx.x;
  const float* hr = h + r * 256;
  float s = 0.f, d = 0.f;
  for (int f = 0; f < 200; ++f) {
    float v = hr[f];
    s += v * att_src[f];
    d += v * att_dst[f];
  }
  as_[r] = s;
  ad_[r] = d;
}

// ---------------- kP: normalized softmax P (max computed inline) ----------------
__global__ __launch_bounds__(256) void kP(const float* __restrict__ as_,
                                          const float* __restrict__ ad_,
                                          float* __restrict__ P) {
  __shared__ float rb[256];
  int t = threadIdx.x, i = blockIdx.x;
  float a0 = as_[t], a1 = as_[256 + t], a2 = as_[512 + t], a3 = as_[768 + t];
  rb[t] = fmaxf(fmaxf(a0, a1), fmaxf(a2, a3));
  __syncthreads();
  for (int st = 128; st > 0; st >>= 1) {
    if (t < st) rb[t] = fmaxf(rb[t], rb[t + st]);
    __syncthreads();
  }
  float maxs = rb[0];
  __syncthreads();
  float ad = ad_[i];
  float mv = maxs + ad;
  float M = mv >= 0.f ? mv : 0.2f * mv;
  float av[4] = {a0, a1, a2, a3};
  float p[4];
  float s = 0.f;
#pragma unroll
  for (int q = 0; q < 4; ++q) {
    float v = av[q] + ad;
    float l = v >= 0.f ? v : 0.2f * v;
    p[q] = __expf(l - M);
    s += p[q];
  }
  rb[t] = s;
  __syncthreads();
  for (int st = 128; st > 0; st >>= 1) {
    if (t < st) rb[t] += rb[t + st];
    __syncthreads();
  }
  float inv = 1.f / rb[0];
#pragma unroll
  for (int q = 0; q < 4; ++q) P[i * 1024 + q * 256 + t] = p[q] * inv;
}

// ---------------- kAttn: split-K GEMM out0 = P @ h (8 K-chunks) ----------------
__global__ __launch_bounds__(256) void kAttn(const float* __restrict__ P,
                                             const float* __restrict__ h,
                                             float* __restrict__ ap) {
  __shared__ __align__(16) float As2[8][64];
  __shared__ __align__(16) float Bs[8][64];
  int t = threadIdx.x;
  int tm = t & 15, tn = t >> 4;
  int i0 = blockIdx.x * 64, f0 = blockIdx.y * 64, j0 = blockIdx.z * 128;
  float acc[4][4] = {};
  for (int k0 = 0; k0 < 128; k0 += 8) {
    for (int i = t; i < 512; i += 256) {
      int m = i >> 3, k = i & 7;
      As2[k][m] = P[(i0 + m) * 1024 + j0 + k0 + k];
    }
    for (int i = t; i < 512; i += 256) {
      int k = i >> 6, n = i & 63;
      Bs[k][n] = h[(j0 + k0 + k) * 256 + f0 + n];
    }
    __syncthreads();
#pragma unroll
    for (int k = 0; k < 8; ++k) {
      float4 a = *(const float4*)&As2[k][tm * 4];
      float4 bq = *(const float4*)&Bs[k][tn * 4];
      float av[4] = {a.x, a.y, a.z, a.w};
      float bv[4] = {bq.x, bq.y, bq.z, bq.w};
#pragma unroll
      for (int i = 0; i < 4; ++i)
#pragma unroll
        for (int j = 0; j < 4; ++j) acc[i][j] += av[i] * bv[j];
    }
    __syncthreads();
  }
#pragma unroll
  for (int i = 0; i < 4; ++i) {
    int r = i0 + tm * 4 + i;
    float4 v = make_float4(acc[i][0], acc[i][1], acc[i][2], acc[i][3]);
    *(float4*)&ap[(blockIdx.z * 1024 + r) * 256 + f0 + tn * 4] = v;
  }
}

// ---------------- kAttnRed ----------------
__global__ __launch_bounds__(256) void kAttnRed(const float* __restrict__ ap,
                                                const float* __restrict__ x,
                                                const float* __restrict__ gat_b,
                                                float* __restrict__ x1) {
  int t = threadIdx.x, r = blockIdx.x;
  if (t >= 200) return;
  float s = 0.f;
#pragma unroll
  for (int z = 0; z < 8; ++z) s += ap[(z * 1024 + r) * 256 + t];
  x1[r * 200 + t] = x[r * 200 + t] + s + gat_b[t];
}

// ---------------- k3 v9: conv1 (VALU) + conv2 (MFMA) ----------------
// grid (16 b, 128 chunks of 8 nodes), block 320 (5 waves).
// conv2 as GEMM: C[p][o] += A[p][k=(nl,c)] * B[o][k];  M=35(pad48) N=40(pad48) K=320.
// 5 waves K-split (64 each, 2 MFMA K-steps x 9 tiles). B from global w2pre (L2-hot).
// LDS 33.9 KB: xbp(10.2K) + tmpA bf16 A-layout (23.6K); C-reduce overlays both.
__global__ __launch_bounds__(320, 2) void k3_conv(const float* __restrict__ x1,
                                                  const unsigned short* __restrict__ w2pre,
                                                  const float* __restrict__ ws,
                                                  float* __restrict__ y3p) {
  __shared__ __align__(16) char smem[33856];
  float* xbp = (float*)smem;                               // 8 nodes x 40 win x 8
  unsigned short* tmpA = (unsigned short*)(smem + 10240);  // 36 rows x 328 (pad) bf16
  int t = threadIdx.x;
  int b = blockIdx.x, nc = blockIdx.y;
  int n0 = nc * 8;
  int wave = t >> 6, lane = t & 63;
  int l15 = lane & 15, quad = lane >> 4;
  // stage 8 node rows into padded windows
  for (int i = t; i < 400; i += 320) {
    int nn = i / 50, q = i % 50;
    float4 v = ((const float4*)(x1 + (b * 1024 + n0 + nn) * 200))[q];
    float vv[4] = {v.x, v.y, v.z, v.w};
#pragma unroll
    for (int m = 0; m < 4; ++m) {
      int j = q * 4 + m;
      xbp[nn * 320 + (j / 5) * 8 + (j % 5)] = vv[m];
    }
  }
  int c1 = t / 7, wg = t % 7;
  float wr[30];
  float s1c = 0.f, sh1c = 0.f;
  if (t < 280) {
    const float* weff = ws + WS_WEFF + c1 * 30;
#pragma unroll
    for (int j = 0; j < 30; ++j) wr[j] = weff[j];
    s1c = ws[WS_S1 + c1];
    sh1c = ws[WS_SH1 + c1];
  }
  __syncthreads();
  // conv1 + bn1 + elu -> tmpA[p][nn*40+c1] (bf16)
  if (t < 280) {
    for (int nn = 0; nn < 8; ++nn) {
      float xq[10][5];
      int xb = nn * 320 + wg * 40;
#pragma unroll
      for (int pi = 0; pi < 10; ++pi) {
        float4 v = *(const float4*)&xbp[xb + pi * 8];
        xq[pi][0] = v.x; xq[pi][1] = v.y; xq[pi][2] = v.z; xq[pi][3] = v.w;
        xq[pi][4] = xbp[xb + pi * 8 + 4];
      }
#pragma unroll
      for (int u = 0; u < 5; ++u) {
        float s = 0.f;
#pragma unroll
        for (int m = 0; m < 6; ++m)
#pragma unroll
          for (int r = 0; r < 5; ++r) s += xq[u + m][r] * wr[m * 5 + r];
        float v = s * s1c + sh1c;
        float e = v > 0.f ? v : __expf(v) - 1.f;
        tmpA[(wg * 5 + u) * 328 + nn * 40 + c1] = (unsigned short)f2bf(e);
      }
    }
  }
  __syncthreads();
  // conv2 MFMA: wave k-range [wave*64, wave*64+64)
  f32x4 acc[3][3];
#pragma unroll
  for (int mt = 0; mt < 3; ++mt)
#pragma unroll
    for (int nt = 0; nt < 3; ++nt) acc[mt][nt] = (f32x4){0.f, 0.f, 0.f, 0.f};
  const unsigned short* bbase = w2pre + nc * 48 * 320;
#pragma unroll
  for (int ks = 0; ks < 2; ++ks) {
    int koff = wave * 64 + ks * 32 + quad * 8;
    short8 a[3], bb[3];
#pragma unroll
    for (int mt = 0; mt < 3; ++mt) {
      int row = mt * 16 + l15;
      row = row > 35 ? 35 : row;  // clamp: rows >=35 discarded in C
      a[mt] = *(const short8*)&tmpA[row * 328 + koff];
    }
#pragma unroll
    for (int nt = 0; nt < 3; ++nt)
      bb[nt] = *(const short8*)&bbase[(nt * 16 + l15) * 320 + koff];
#pragma unroll
    for (int mt = 0; mt < 3; ++mt)
#pragma unroll
      for (int nt = 0; nt < 3; ++nt)
        acc[mt][nt] = __builtin_amdgcn_mfma_f32_16x16x32_bf16(a[mt], bb[nt], acc[mt][nt], 0, 0, 0);
  }
  __syncthreads();
  // cross-wave C reduction (red overlays xbp+tmpA, both dead)
  float* red0 = (float*)smem;           // 48x49
  float* red1 = red0 + 48 * 49;         // 48x49
  if (wave < 2) {
    float* r = wave ? red1 : red0;
#pragma unroll
    for (int mt = 0; mt < 3; ++mt)
#pragma unroll
      for (int nt = 0; nt < 3; ++nt)
#pragma unroll
        for (int q = 0; q < 4; ++q)
          r[(mt * 16 + quad * 4 + q) * 49 + nt * 16 + l15] = acc[mt][nt][q];
  }
  __syncthreads();
  if (wave == 2 || wave == 3) {
    float* r = (wave == 3) ? red1 : red0;
#pragma unroll
    for (int mt = 0; mt < 3; ++mt)
#pragma unroll
      for (int nt = 0; nt < 3; ++nt)
#pragma unroll
        for (int q = 0; q < 4; ++q)
          r[(mt * 16 + quad * 4 + q) * 49 + nt * 16 + l15] += acc[mt][nt][q];
  }
  __syncthreads();
  if (wave == 4) {
#pragma unroll
    for (int mt = 0; mt < 3; ++mt)
#pragma unroll
      for (int nt = 0; nt < 3; ++nt)
#pragma unroll
        for (int q = 0; q < 4; ++q)
          red0[(mt * 16 + quad * 4 + q) * 49 + nt * 16 + l15] += acc[mt][nt][q];
  }
  __syncthreads();
  float* dst = y3p + (b * 128 + nc) * 1400;
  for (int idx = t; idx < 1400; idx += 320) {
    int o = idx / 35, p = idx % 35;
    dst[idx] = red0[p * 49 + o] + red1[p * 49 + o];
  }
}

// ---------------- k4a: reduce 128 partials + bn2 + elu -> y4 ----------------
__global__ __launch_bounds__(256) void k4a_red(const float* __restrict__ y3p,
                                               const float* __restrict__ ws,
                                               float* __restrict__ y4) {
  int t = threadIdx.x;
  if (t >= 200) return;
  int b = blockIdx.x;
  int idx = blockIdx.y * 200 + t;
  float s = 0.f;
#pragma unroll 4
  for (int q = 0; q < 128; ++q) s += y3p[(b * 128 + q) * 1400 + idx];
  int o = idx / 35;
  float v = s * ws[WS_S2 + o] + ws[WS_SH2 + o];
  y4[b * 1400 + idx] = v > 0.f ? v : __expf(v) - 1.f;
}

// ---------------- k4b: projc + rearrange -> y5 ----------------
__global__ __launch_bounds__(256) void k4b_proj(const float* __restrict__ y4,
                                                const float* __restrict__ projc_w,
                                                const float* __restrict__ projc_b,
                                                float* __restrict__ y5) {
  __shared__ __align__(16) float tls[1400];
  int t = threadIdx.x, b = blockIdx.x;
  for (int i = t; i < 350; i += 256)
    ((float4*)tls)[i] = ((const float4*)(y4 + b * 1400))[i];
  __syncthreads();
  for (int idx = t; idx < 1400; idx += 256) {
    int p = idx / 40, e = idx % 40;
    float acc = projc_b[e];
    for (int o = 0; o < 40; ++o) acc += tls[o * 35 + p] * projc_w[e * 40 + o];
    y5[b * 1400 + idx] = acc;
  }
}

// ---------------- k5: split-K FC1 partials ----------------
__global__ __launch_bounds__(256) void k5_fc1(const float* __restrict__ y5,
                                              const float* __restrict__ W1,
                                              float* __restrict__ zp) {
  __shared__ __align__(16) float yls[3200];
  int t = threadIdx.x;
  int nc = blockIdx.x, kc = blockIdx.y;  // (32, 7)
  for (int i = t; i < 800; i += 256) {
    int bb = i / 50, q = i % 50;
    ((float4*)yls)[bb * 50 + q] = *(const float4*)(y5 + bb * 1400 + kc * 200 + q * 4);
  }
  __syncthreads();
  int nl = t & 31, bg = t >> 5;
  int n = nc * 32 + nl;
  float acc0 = 0.f, acc1 = 0.f;
  const float* y0 = yls + (bg * 2) * 200;
  const float* y1 = yls + (bg * 2 + 1) * 200;
  for (int k = 0; k < 200; ++k) {
    float w = W1[(kc * 200 + k) * 1024 + n];
    acc0 += y0[k] * w;
    acc1 += y1[k] * w;
  }
  zp[(kc * 16 + bg * 2) * 1024 + n] = acc0;
  zp[(kc * 16 + bg * 2 + 1) * 1024 + n] = acc1;
}

// ---------------- k6: split-K FC2 partials, gelu(z) on the fly ----------------
__global__ __launch_bounds__(256) void k6_fc2(const float* __restrict__ zp,
                                              const float* __restrict__ b1,
                                              const float* __restrict__ W2,
                                              float* __restrict__ z2p) {
  __shared__ __align__(16) float gls[2048];
  int t = threadIdx.x;
  int nc = blockIdx.x, kc = blockIdx.y;  // (32, 8)
  for (int i = t; i < 2048; i += 256) {
    int bb = i >> 7, kk = i & 127;
    int np = kc * 128 + kk;
    float s = b1[np];
#pragma unroll
    for (int j = 0; j < 7; ++j) s += zp[(j * 16 + bb) * 1024 + np];
    gls[i] = 0.5f * s * (1.f + erff(s * 0.70710678f));
  }
  __syncthreads();
  int nl = t & 31, bg = t >> 5;
  int n = nc * 32 + nl;
  float acc0 = 0.f, acc1 = 0.f;
  const float* g0 = gls + (bg * 2) * 128;
  const float* g1 = gls + (bg * 2 + 1) * 128;
  for (int k = 0; k < 128; ++k) {
    float w = W2[(kc * 128 + k) * 1024 + n];
    acc0 += g0[k] * w;
    acc1 += g1[k] * w;
  }
  z2p[(kc * 16 + bg * 2) * 1024 + n] = acc0;
  z2p[(kc * 16 + bg * 2 + 1) * 1024 + n] = acc1;
}

// ---------------- k7: z recompute + FC2 reduce + residual + LayerNorm ----------------
__global__ __launch_bounds__(256) void k7_ln(const float* __restrict__ zp,
                                             const float* __restrict__ z2p,
                                             const float* __restrict__ b1,
                                             const float* __restrict__ b2,
                                             const float* __restrict__ ln_g,
                                             const float* __restrict__ ln_b,
                                             float* __restrict__ out) {
  __shared__ float r1[256], r2[256];
  int t = threadIdx.x, b = blockIdx.x;
  float4 v = *(const float4*)(b1 + t * 4);
  float4 bb2 = *(const float4*)(b2 + t * 4);
  v.x += bb2.x; v.y += bb2.y; v.z += bb2.z; v.w += bb2.w;
#pragma unroll
  for (int kc = 0; kc < 7; ++kc) {
    float4 p = *(const float4*)(zp + (kc * 16 + b) * 1024 + t * 4);
    v.x += p.x; v.y += p.y; v.z += p.z; v.w += p.w;
  }
#pragma unroll
  for (int kc = 0; kc < 8; ++kc) {
    float4 p = *(const float4*)(z2p + (kc * 16 + b) * 1024 + t * 4);
    v.x += p.x; v.y += p.y; v.z += p.z; v.w += p.w;
  }
  r1[t] = v.x + v.y + v.z + v.w;
  r2[t] = v.x * v.x + v.y * v.y + v.z * v.z + v.w * v.w;
  __syncthreads();
  for (int s = 128; s > 0; s >>= 1) {
    if (t < s) {
      r1[t] += r1[t + s];
      r2[t] += r2[t + s];
    }
    __syncthreads();
  }
  float mu = r1[0] * (1.f / 1024.f);
  float var = r2[0] * (1.f / 1024.f) - mu * mu;
  float rstd = rsqrtf(var + 1e-5f);
  float4 gg = *(const float4*)(ln_g + t * 4);
  float4 bb = *(const float4*)(ln_b + t * 4);
  float4 o;
  o.x = (v.x - mu) * rstd * gg.x + bb.x;
  o.y = (v.y - mu) * rstd * gg.y + bb.y;
  o.z = (v.z - mu) * rstd * gg.z + bb.z;
  o.w = (v.w - mu) * rstd * gg.w + bb.w;
  *(float4*)(out + b * 1024 + t * 4) = o;
}

extern "C" void kernel_launch(void* const* d_in, const int* in_sizes, int n_in,
                              void* d_out, int out_size, void* d_ws, size_t ws_size,
                              hipStream_t stream) {
  (void)in_sizes; (void)n_in; (void)out_size; (void)ws_size;
  const float* x       = (const float*)d_in[0];
  const float* gat_W   = (const float*)d_in[1];
  const float* att_src = (const float*)d_in[2];
  const float* att_dst = (const float*)d_in[3];
  const float* gat_b   = (const float*)d_in[4];
  const float* conv1_w = (const float*)d_in[5];
  const float* conv2_w = (const float*)d_in[11];
  const float* projc_w = (const float*)d_in[17];
  const float* projc_b = (const float*)d_in[18];
  const float* W1      = (const float*)d_in[19];
  const float* b1      = (const float*)d_in[20];
  const float* W2      = (const float*)d_in[21];
  const float* b2      = (const float*)d_in[22];
  const float* ln_g    = (const float*)d_in[23];
  const float* ln_b    = (const float*)d_in[24];
  float* ws  = (float*)d_ws;
  float* out = (float*)d_out;

  hipLaunchKernelGGL(k0_prep, dim3(7905), dim3(256), 0, stream, gat_W, conv1_w,
                     (const float*)d_in[6], (const float*)d_in[7], (const float*)d_in[8],
                     (const float*)d_in[9], (const float*)d_in[10], (const float*)d_in[12],
                     (const float*)d_in[13], (const float*)d_in[14], (const float*)d_in[15],
                     (const float*)d_in[16], conv2_w, ws);
  hipLaunchKernelGGL(k1_mfma, dim3(256, 4), dim3(256), 0, stream, x,
                     (const unsigned short*)(ws + WS_WPT), gat_b, ws + WS_H, ws + WS_X1);
  hipLaunchKernelGGL(k1b_scores, dim3(4), dim3(256), 0, stream, ws + WS_H, att_src, att_dst,
                     ws + WS_AS, ws + WS_AD);
  hipLaunchKernelGGL(kP, dim3(1024), dim3(256), 0, stream, ws + WS_AS, ws + WS_AD, ws + WS_P);
  hipLaunchKernelGGL(kAttn, dim3(16, 4, 8), dim3(256), 0, stream, ws + WS_P, ws + WS_H,
                     ws + WS_AP);
  hipLaunchKernelGGL(kAttnRed, dim3(1024), dim3(256), 0, stream, ws + WS_AP, x, gat_b,
                     ws + WS_X1);
  hipLaunchKernelGGL(k3_conv, dim3(16, 128), dim3(320), 0, stream, ws + WS_X1,
                     (const unsigned short*)(ws + WS_W2P), ws, ws + WS_Y3P);
  hipLaunchKernelGGL(k4a_red, dim3(16, 7), dim3(256), 0, stream, ws + WS_Y3P, ws, ws + WS_Y4);
  hipLaunchKernelGGL(k4b_proj, dim3(16), dim3(256), 0, stream, ws + WS_Y4, projc_w, projc_b,
                     ws + WS_Y5);
  hipLaunchKernelGGL(k5_fc1, dim3(32, 7), dim3(256), 0, stream, ws + WS_Y5, W1, ws + WS_ZP);
  hipLaunchKernelGGL(k6_fc2, dim3(32, 8), dim3(256), 0, stream, ws + WS_ZP, b1, W2,
                     ws + WS_Z2P);
  hipLaunchKernelGGL(k7_ln, dim3(16), dim3(256), 0, stream, ws + WS_ZP, ws + WS_Z2P, b1, b2,
                     ln_g, ln_b, out);
}

// Round 10
// 245.591 us; speedup vs baseline: 1.3974x; 1.1418x over previous
//
#include <hip/hip_runtime.h>
#include <math.h>

typedef __attribute__((ext_vector_type(8))) short short8;
typedef __attribute__((ext_vector_type(4))) float f32x4;

__device__ __forceinline__ unsigned f2bf(float f) {
  unsigned u = __float_as_uint(f);
  return (u + 0x7FFFu + ((u >> 16) & 1u)) >> 16;
}
__device__ __forceinline__ unsigned pk2(float lo, float hi) {
  return f2bf(lo) | (f2bf(hi) << 16);
}

// ---------------- workspace layout (float offsets) ----------------
#define WS_X1    0                    // 16384*200
#define WS_W2P   3328000              // w2pre: 128*48*320 bf16 shorts
#define WS_AS    4966400              // 1024
#define WS_AD    4967424              // 1024
#define WS_WEFB  4968464              // weffB: 48*32 bf16 (768 floats)
#define WS_S1    4969664              // 40
#define WS_SH1   4969704              // 40
#define WS_S2    4969744              // 40
#define WS_SH2   4969784              // 40
#define WS_H     4970496              // 1024*256
#define WS_P     5232640              // 1024*1024 normalized softmax P
#define WS_AP    6281216              // 8*1024*256 attention split-K partials
#define WS_Y3P   WS_P                 // 16*128*1400 (overlays P+AP; dead by k3)
#define WS_Y4    8378368              // 16*1400
#define WS_Y5    8400768              // 16*1400
#define WS_ZP    8455936              // 7*16*1024
#define WS_Z2P   8570624              // 8*16*1024
#define WS_WPT   8701696              // 256*224 bf16: gat_W^T zero-padded
// end 8,730,368 floats = 34.9 MB

// ---------------- k0: params + wpadT + weffB + w2pre (LDS-staged coalesced) ----------------
__global__ __launch_bounds__(256) void k0_prep(const float* __restrict__ gat_W,
                        const float* __restrict__ conv1_w, const float* __restrict__ conv1_b,
                        const float* __restrict__ bn1_g, const float* __restrict__ bn1_b,
                        const float* __restrict__ bn1_m, const float* __restrict__ bn1_v,
                        const float* __restrict__ conv2_b,
                        const float* __restrict__ bn2_g, const float* __restrict__ bn2_b,
                        const float* __restrict__ bn2_m, const float* __restrict__ bn2_v,
                        const float* __restrict__ w2,
                        float* __restrict__ ws) {
  int bx = blockIdx.x, t = threadIdx.x;
  if (bx < 224) {
    unsigned short* wpt = (unsigned short*)(ws + WS_WPT);
    int idx = bx * 256 + t;  // n*224 + k
    int n = idx / 224, k = idx % 224;
    float v = (n < 200 && k < 200) ? gat_W[k * 200 + n] : 0.f;
    wpt[idx] = (unsigned short)f2bf(v);
    return;
  }
  if (bx == 224) {
    if (t < 48) {
      // weffB[c][k] bf16: pooled conv1 kernel, zero-padded to 48x32
      unsigned short* wb = (unsigned short*)(ws + WS_WEFB);
      float wv[30];
      if (t < 40) {
        for (int j = 0; j < 30; ++j) {
          float s = 0.f;
          for (int tt = 0; tt < 5; ++tt) {
            int k = j - tt;
            if (k >= 0 && k < 26) s += conv1_w[t * 26 + k];
          }
          wv[j] = s * 0.2f;
        }
      }
      for (int k = 0; k < 32; ++k)
        wb[t * 32 + k] = (unsigned short)f2bf((t < 40 && k < 30) ? wv[k] : 0.f);
    }
    if (t < 40) {
      float s1 = bn1_g[t] * rsqrtf(bn1_v[t] + 1e-5f);
      ws[WS_S1 + t] = s1;
      ws[WS_SH1 + t] = bn1_b[t] + (conv1_b[t] - bn1_m[t]) * s1;
      float s2 = bn2_g[t] * rsqrtf(bn2_v[t] + 1e-5f);
      ws[WS_S2 + t] = s2;
      ws[WS_SH2 + t] = bn2_b[t] + (conv2_b[t] - bn2_m[t]) * s2;
    }
    return;
  }
  // w2pre: 768 blocks, each (c8, o-group of 8): stage via LDS, write coalesced
  __shared__ unsigned short lds[2560];
  int q = bx - 225;       // [0,768)
  int c8 = q / 6, o0 = (q % 6) * 8;
  unsigned short* w2p = (unsigned short*)(ws + WS_W2P);
#pragma unroll
  for (int i = 0; i < 10; ++i) {
    int e = i * 256 + t;  // < 2560
    int o = e / 320, rr = e % 320;
    int c = rr / 8, nl = rr % 8;
    int oa = o0 + o;
    float v = (oa < 40) ? w2[(oa * 40 + c) * 1024 + c8 * 8 + nl] : 0.f;
    lds[o * 320 + nl * 40 + c] = (unsigned short)f2bf(v);
  }
  __syncthreads();
  uint4* src = (uint4*)lds;                              // 320 uint4
  uint4* dst = (uint4*)(w2p + (c8 * 48 + o0) * 320);
  for (int i = t; i < 320; i += 256) dst[i] = src[i];
}

// ---------------- k1: MFMA bf16 GEMM h = x @ W (K=200 pad 224) ----------------
__global__ __launch_bounds__(256) void k1_mfma(const float* __restrict__ x,
                                               const unsigned short* __restrict__ wpt,
                                               const float* __restrict__ gat_b,
                                               float* __restrict__ h,
                                               float* __restrict__ x1) {
  __shared__ unsigned short Bt[64 * 232];
  __shared__ unsigned short As[2][64 * 40];
  int t = threadIdx.x;
  int wave = t >> 6, lane = t & 63;
  int m16 = lane & 15, quad = lane >> 4;
  int row0 = blockIdx.x * 64, n0 = blockIdx.y * 64;
  for (int i = t; i < 1792; i += 256) {
    int row = i / 28, ch = i % 28;
    *(short8*)&Bt[row * 232 + ch * 8] = *(const short8*)&wpt[(n0 + row) * 224 + ch * 8];
  }
  {
    int m = t >> 2, kq = (t & 3) * 8;
    const float* xr = x + (row0 + m) * 200 + kq;
    float4 a = *(const float4*)xr;
    float4 b = *(const float4*)(xr + 4);
    uint4 pv;
    pv.x = pk2(a.x, a.y); pv.y = pk2(a.z, a.w);
    pv.z = pk2(b.x, b.y); pv.w = pk2(b.z, b.w);
    *(uint4*)&As[0][m * 40 + kq] = pv;
  }
  __syncthreads();
  f32x4 acc0 = {0.f, 0.f, 0.f, 0.f}, acc1 = acc0, acc2 = acc0, acc3 = acc0;
  int buf = 0;
  for (int s = 0; s < 7; ++s) {
    if (s < 6) {
      int m = t >> 2, kq = (t & 3) * 8;
      int kg = (s + 1) * 32 + kq;
      const float* xr = x + (row0 + m) * 200;
      uint4 pv;
      if (kg + 8 <= 200) {
        float4 a = *(const float4*)(xr + kg);
        float4 b = *(const float4*)(xr + kg + 4);
        pv.x = pk2(a.x, a.y); pv.y = pk2(a.z, a.w);
        pv.z = pk2(b.x, b.y); pv.w = pk2(b.z, b.w);
      } else {
        float e[8];
#pragma unroll
        for (int q = 0; q < 8; ++q) e[q] = (kg + q < 200) ? xr[kg + q] : 0.f;
        pv.x = pk2(e[0], e[1]); pv.y = pk2(e[2], e[3]);
        pv.z = pk2(e[4], e[5]); pv.w = pk2(e[6], e[7]);
      }
      *(uint4*)&As[buf ^ 1][m * 40 + kq] = pv;
    }
    short8 af = *(const short8*)&As[buf][(wave * 16 + m16) * 40 + quad * 8];
    int kb = s * 32 + quad * 8;
    short8 b0 = *(const short8*)&Bt[(0 * 16 + m16) * 232 + kb];
    short8 b1 = *(const short8*)&Bt[(1 * 16 + m16) * 232 + kb];
    short8 b2 = *(const short8*)&Bt[(2 * 16 + m16) * 232 + kb];
    short8 b3 = *(const short8*)&Bt[(3 * 16 + m16) * 232 + kb];
    acc0 = __builtin_amdgcn_mfma_f32_16x16x32_bf16(af, b0, acc0, 0, 0, 0);
    acc1 = __builtin_amdgcn_mfma_f32_16x16x32_bf16(af, b1, acc1, 0, 0, 0);
    acc2 = __builtin_amdgcn_mfma_f32_16x16x32_bf16(af, b2, acc2, 0, 0, 0);
    acc3 = __builtin_amdgcn_mfma_f32_16x16x32_bf16(af, b3, acc3, 0, 0, 0);
    __syncthreads();
    buf ^= 1;
  }
  f32x4 accs[4] = {acc0, acc1, acc2, acc3};
  if (blockIdx.x < 16) {
#pragma unroll
    for (int nt = 0; nt < 4; ++nt)
#pragma unroll
      for (int r = 0; r < 4; ++r) {
        int row = row0 + wave * 16 + quad * 4 + r;
        h[row * 256 + n0 + nt * 16 + m16] = accs[nt][r];
      }
  } else {
#pragma unroll
    for (int nt = 0; nt < 4; ++nt) {
      int col = n0 + nt * 16 + m16;
      if (col < 200) {
#pragma unroll
        for (int r = 0; r < 4; ++r) {
          int row = row0 + wave * 16 + quad * 4 + r;
          x1[row * 200 + col] = x[row * 200 + col] + accs[nt][r] + gat_b[col];
        }
      }
    }
  }
}

// ---------------- k1b: attention scores — wave-per-row ----------------
__global__ __launch_bounds__(256) void k1b_scores(const float* __restrict__ h,
                                                  const float* __restrict__ att_src,
                                                  const float* __restrict__ att_dst,
                                                  float* __restrict__ as_,
                                                  float* __restrict__ ad_) {
  int t = threadIdx.x;
  int wave = t >> 6, lane = t & 63;
  int r = blockIdx.x * 4 + wave;
  float s = 0.f, d = 0.f;
  if (lane < 50) {
    float4 v = *(const float4*)(h + r * 256 + lane * 4);
    float4 a = *(const float4*)(att_src + lane * 4);
    float4 dd = *(const float4*)(att_dst + lane * 4);
    s = v.x * a.x + v.y * a.y + v.z * a.z + v.w * a.w;
    d = v.x * dd.x + v.y * dd.y + v.z * dd.z + v.w * dd.w;
  }
#pragma unroll
  for (int off = 32; off > 0; off >>= 1) {
    s += __shfl_down(s, off);
    d += __shfl_down(d, off);
  }
  if (lane == 0) {
    as_[r] = s;
    ad_[r] = d;
  }
}

// ---------------- kP: normalized softmax P (max computed inline) ----------------
__global__ __launch_bounds__(256) void kP(const float* __restrict__ as_,
                                          const float* __restrict__ ad_,
                                          float* __restrict__ P) {
  __shared__ float rb[256];
  int t = threadIdx.x, i = blockIdx.x;
  float a0 = as_[t], a1 = as_[256 + t], a2 = as_[512 + t], a3 = as_[768 + t];
  rb[t] = fmaxf(fmaxf(a0, a1), fmaxf(a2, a3));
  __syncthreads();
  for (int st = 128; st > 0; st >>= 1) {
    if (t < st) rb[t] = fmaxf(rb[t], rb[t + st]);
    __syncthreads();
  }
  float maxs = rb[0];
  __syncthreads();
  float ad = ad_[i];
  float mv = maxs + ad;
  float M = mv >= 0.f ? mv : 0.2f * mv;
  float av[4] = {a0, a1, a2, a3};
  float p[4];
  float s = 0.f;
#pragma unroll
  for (int q = 0; q < 4; ++q) {
    float v = av[q] + ad;
    float l = v >= 0.f ? v : 0.2f * v;
    p[q] = __expf(l - M);
    s += p[q];
  }
  rb[t] = s;
  __syncthreads();
  for (int st = 128; st > 0; st >>= 1) {
    if (t < st) rb[t] += rb[t + st];
    __syncthreads();
  }
  float inv = 1.f / rb[0];
#pragma unroll
  for (int q = 0; q < 4; ++q) P[i * 1024 + q * 256 + t] = p[q] * inv;
}

// ---------------- kAttn: split-K GEMM out0 = P @ h (8 K-chunks) ----------------
__global__ __launch_bounds__(256) void kAttn(const float* __restrict__ P,
                                             const float* __restrict__ h,
                                             float* __restrict__ ap) {
  __shared__ __align__(16) float As2[8][64];
  __shared__ __align__(16) float Bs[8][64];
  int t = threadIdx.x;
  int tm = t & 15, tn = t >> 4;
  int i0 = blockIdx.x * 64, f0 = blockIdx.y * 64, j0 = blockIdx.z * 128;
  float acc[4][4] = {};
  for (int k0 = 0; k0 < 128; k0 += 8) {
    for (int i = t; i < 512; i += 256) {
      int m = i >> 3, k = i & 7;
      As2[k][m] = P[(i0 + m) * 1024 + j0 + k0 + k];
    }
    for (int i = t; i < 512; i += 256) {
      int k = i >> 6, n = i & 63;
      Bs[k][n] = h[(j0 + k0 + k) * 256 + f0 + n];
    }
    __syncthreads();
#pragma unroll
    for (int k = 0; k < 8; ++k) {
      float4 a = *(const float4*)&As2[k][tm * 4];
      float4 bq = *(const float4*)&Bs[k][tn * 4];
      float av[4] = {a.x, a.y, a.z, a.w};
      float bv[4] = {bq.x, bq.y, bq.z, bq.w};
#pragma unroll
      for (int i = 0; i < 4; ++i)
#pragma unroll
        for (int j = 0; j < 4; ++j) acc[i][j] += av[i] * bv[j];
    }
    __syncthreads();
  }
#pragma unroll
  for (int i = 0; i < 4; ++i) {
    int r = i0 + tm * 4 + i;
    float4 v = make_float4(acc[i][0], acc[i][1], acc[i][2], acc[i][3]);
    *(float4*)&ap[(blockIdx.z * 1024 + r) * 256 + f0 + tn * 4] = v;
  }
}

// ---------------- kAttnRed ----------------
__global__ __launch_bounds__(256) void kAttnRed(const float* __restrict__ ap,
                                                const float* __restrict__ x,
                                                const float* __restrict__ gat_b,
                                                float* __restrict__ x1) {
  int t = threadIdx.x, r = blockIdx.x;
  if (t >= 200) return;
  float s = 0.f;
#pragma unroll
  for (int z = 0; z < 8; ++z) s += ap[(z * 1024 + r) * 256 + t];
  x1[r * 200 + t] = x[r * 200 + t] + s + gat_b[t];
}

// ---------------- k3 v10: conv1 (MFMA) + conv2 (MFMA) ----------------
// grid (16 b, 128 chunks of 8 nodes), block 320 (5 waves).
// conv1 GEMM: A[m=(nn,p)][k=j] overlapping windows bf16, B=weffB, M=280(pad288) N=48 K=32.
// epilogue: bn1+elu in regs -> t2 (conv2 A-layout). conv2 as R9 (proven).
__global__ __launch_bounds__(320, 2) void k3_conv(const float* __restrict__ x1,
                                                  const unsigned short* __restrict__ w2pre,
                                                  const unsigned short* __restrict__ weffB,
                                                  const float* __restrict__ ws,
                                                  float* __restrict__ y3p) {
  __shared__ __align__(16) char smem[48448];
  float* xbp = (float*)smem;                              // 8 x 200 fp32 (6400 B)
  unsigned short* tA = (unsigned short*)(smem + 6400);    // 288 x 32 bf16 (18432 B)
  unsigned short* t2 = (unsigned short*)(smem + 24832);   // 36 x 328 bf16 (23616 B)
  int t = threadIdx.x;
  int b = blockIdx.x, nc = blockIdx.y;
  int n0 = nc * 8;
  int wave = t >> 6, lane = t & 63;
  int l15 = lane & 15, quad = lane >> 4;
  // stage x rows (coalesced)
  for (int i = t; i < 400; i += 320) {
    int nn = i / 50, q = i % 50;
    ((float4*)(xbp + nn * 200))[q] = ((const float4*)(x1 + (b * 1024 + n0 + nn) * 200))[q];
  }
  __syncthreads();
  // A-pack: row m=t -> windows x[p*5 .. p*5+29] bf16, pad k30,31=0
  if (t < 280) {
    int nn = t / 35, p = t % 35;
    const float* xr = xbp + nn * 200 + p * 5;
    uint pv[16];
#pragma unroll
    for (int kk = 0; kk < 15; ++kk) pv[kk] = pk2(xr[kk * 2], xr[kk * 2 + 1]);
    pv[15] = 0u;
    uint4* dst = (uint4*)(tA + t * 32);
    dst[0] = make_uint4(pv[0], pv[1], pv[2], pv[3]);
    dst[1] = make_uint4(pv[4], pv[5], pv[6], pv[7]);
    dst[2] = make_uint4(pv[8], pv[9], pv[10], pv[11]);
    dst[3] = make_uint4(pv[12], pv[13], pv[14], pv[15]);
  } else if (t < 288) {
    uint4 z = make_uint4(0u, 0u, 0u, 0u);
    uint4* dst = (uint4*)(tA + t * 32);
    dst[0] = z; dst[1] = z; dst[2] = z; dst[3] = z;
  }
  __syncthreads();
  // conv1 MFMA: wave w -> m-tiles [w*4, w*4+nmt)
  {
    int mt0 = wave * 4;
    int nmt = wave < 4 ? 4 : 2;
    short8 bw[3];
    float s1v[3] = {0.f, 0.f, 0.f}, sh1v[3] = {0.f, 0.f, 0.f};
#pragma unroll
    for (int nt = 0; nt < 3; ++nt) {
      bw[nt] = *(const short8*)&weffB[(nt * 16 + l15) * 32 + quad * 8];
      int c = nt * 16 + l15;
      if (c < 40) {
        s1v[nt] = ws[WS_S1 + c];
        sh1v[nt] = ws[WS_SH1 + c];
      }
    }
    for (int mi = 0; mi < nmt; ++mi) {
      int mt = mt0 + mi;
      short8 a = *(const short8*)&tA[(mt * 16 + l15) * 32 + quad * 8];
#pragma unroll
      for (int nt = 0; nt < 3; ++nt) {
        int c = nt * 16 + l15;
        if (c >= 40) continue;
        f32x4 c4 = {0.f, 0.f, 0.f, 0.f};
        c4 = __builtin_amdgcn_mfma_f32_16x16x32_bf16(a, bw[nt], c4, 0, 0, 0);
#pragma unroll
        for (int r = 0; r < 4; ++r) {
          int m = mt * 16 + quad * 4 + r;
          if (m < 280) {
            float v = c4[r] * s1v[nt] + sh1v[nt];
            float e = v > 0.f ? v : __expf(v) - 1.f;
            int p = m % 35, nn = m / 35;
            t2[p * 328 + nn * 40 + c] = (unsigned short)f2bf(e);
          }
        }
      }
    }
  }
  __syncthreads();
  // conv2 MFMA (R9-proven): wave k-range [wave*64, wave*64+64)
  f32x4 acc[3][3];
#pragma unroll
  for (int mt = 0; mt < 3; ++mt)
#pragma unroll
    for (int nt = 0; nt < 3; ++nt) acc[mt][nt] = (f32x4){0.f, 0.f, 0.f, 0.f};
  const unsigned short* bbase = w2pre + nc * 48 * 320;
#pragma unroll
  for (int ks = 0; ks < 2; ++ks) {
    int koff = wave * 64 + ks * 32 + quad * 8;
    short8 a[3], bb[3];
#pragma unroll
    for (int mt = 0; mt < 3; ++mt) {
      int row = mt * 16 + l15;
      row = row > 35 ? 35 : row;
      a[mt] = *(const short8*)&t2[row * 328 + koff];
    }
#pragma unroll
    for (int nt = 0; nt < 3; ++nt)
      bb[nt] = *(const short8*)&bbase[(nt * 16 + l15) * 320 + koff];
#pragma unroll
    for (int mt = 0; mt < 3; ++mt)
#pragma unroll
      for (int nt = 0; nt < 3; ++nt)
        acc[mt][nt] = __builtin_amdgcn_mfma_f32_16x16x32_bf16(a[mt], bb[nt], acc[mt][nt], 0, 0, 0);
  }
  __syncthreads();
  float* red0 = (float*)smem;       // 48x49
  float* red1 = red0 + 48 * 49;
  if (wave < 2) {
    float* r = wave ? red1 : red0;
#pragma unroll
    for (int mt = 0; mt < 3; ++mt)
#pragma unroll
      for (int nt = 0; nt < 3; ++nt)
#pragma unroll
        for (int q = 0; q < 4; ++q)
          r[(mt * 16 + quad * 4 + q) * 49 + nt * 16 + l15] = acc[mt][nt][q];
  }
  __syncthreads();
  if (wave == 2 || wave == 3) {
    float* r = (wave == 3) ? red1 : red0;
#pragma unroll
    for (int mt = 0; mt < 3; ++mt)
#pragma unroll
      for (int nt = 0; nt < 3; ++nt)
#pragma unroll
        for (int q = 0; q < 4; ++q)
          r[(mt * 16 + quad * 4 + q) * 49 + nt * 16 + l15] += acc[mt][nt][q];
  }
  __syncthreads();
  if (wave == 4) {
#pragma unroll
    for (int mt = 0; mt < 3; ++mt)
#pragma unroll
      for (int nt = 0; nt < 3; ++nt)
#pragma unroll
        for (int q = 0; q < 4; ++q)
          red0[(mt * 16 + quad * 4 + q) * 49 + nt * 16 + l15] += acc[mt][nt][q];
  }
  __syncthreads();
  float* dst = y3p + (b * 128 + nc) * 1400;
  for (int idx = t; idx < 1400; idx += 320) {
    int o = idx / 35, p = idx % 35;
    dst[idx] = red0[p * 49 + o] + red1[p * 49 + o];
  }
}

// ---------------- k4a: reduce 128 partials + bn2 + elu -> y4 ----------------
__global__ __launch_bounds__(256) void k4a_red(const float* __restrict__ y3p,
                                               const float* __restrict__ ws,
                                               float* __restrict__ y4) {
  int t = threadIdx.x;
  if (t >= 200) return;
  int b = blockIdx.x;
  int idx = blockIdx.y * 200 + t;
  float s = 0.f;
#pragma unroll 4
  for (int q = 0; q < 128; ++q) s += y3p[(b * 128 + q) * 1400 + idx];
  int o = idx / 35;
  float v = s * ws[WS_S2 + o] + ws[WS_SH2 + o];
  y4[b * 1400 + idx] = v > 0.f ? v : __expf(v) - 1.f;
}

// ---------------- k4b: projc + rearrange -> y5 ----------------
__global__ __launch_bounds__(256) void k4b_proj(const float* __restrict__ y4,
                                                const float* __restrict__ projc_w,
                                                const float* __restrict__ projc_b,
                                                float* __restrict__ y5) {
  __shared__ __align__(16) float tls[1400];
  int t = threadIdx.x, b = blockIdx.x;
  for (int i = t; i < 350; i += 256)
    ((float4*)tls)[i] = ((const float4*)(y4 + b * 1400))[i];
  __syncthreads();
  for (int idx = t; idx < 1400; idx += 256) {
    int p = idx / 40, e = idx % 40;
    float acc = projc_b[e];
    for (int o = 0; o < 40; ++o) acc += tls[o * 35 + p] * projc_w[e * 40 + o];
    y5[b * 1400 + idx] = acc;
  }
}

// ---------------- k5: split-K FC1 partials ----------------
__global__ __launch_bounds__(256) void k5_fc1(const float* __restrict__ y5,
                                              const float* __restrict__ W1,
                                              float* __restrict__ zp) {
  __shared__ __align__(16) float yls[3200];
  int t = threadIdx.x;
  int nc = blockIdx.x, kc = blockIdx.y;  // (32, 7)
  for (int i = t; i < 800; i += 256) {
    int bb = i / 50, q = i % 50;
    ((float4*)yls)[bb * 50 + q] = *(const float4*)(y5 + bb * 1400 + kc * 200 + q * 4);
  }
  __syncthreads();
  int nl = t & 31, bg = t >> 5;
  int n = nc * 32 + nl;
  float acc0 = 0.f, acc1 = 0.f;
  const float* y0 = yls + (bg * 2) * 200;
  const float* y1 = yls + (bg * 2 + 1) * 200;
  for (int k = 0; k < 200; ++k) {
    float w = W1[(kc * 200 + k) * 1024 + n];
    acc0 += y0[k] * w;
    acc1 += y1[k] * w;
  }
  zp[(kc * 16 + bg * 2) * 1024 + n] = acc0;
  zp[(kc * 16 + bg * 2 + 1) * 1024 + n] = acc1;
}

// ---------------- k6: split-K FC2 partials, gelu(z) on the fly ----------------
__global__ __launch_bounds__(256) void k6_fc2(const float* __restrict__ zp,
                                              const float* __restrict__ b1,
                                              const float* __restrict__ W2,
                                              float* __restrict__ z2p) {
  __shared__ __align__(16) float gls[2048];
  int t = threadIdx.x;
  int nc = blockIdx.x, kc = blockIdx.y;  // (32, 8)
  for (int i = t; i < 2048; i += 256) {
    int bb = i >> 7, kk = i & 127;
    int np = kc * 128 + kk;
    float s = b1[np];
#pragma unroll
    for (int j = 0; j < 7; ++j) s += zp[(j * 16 + bb) * 1024 + np];
    gls[i] = 0.5f * s * (1.f + erff(s * 0.70710678f));
  }
  __syncthreads();
  int nl = t & 31, bg = t >> 5;
  int n = nc * 32 + nl;
  float acc0 = 0.f, acc1 = 0.f;
  const float* g0 = gls + (bg * 2) * 128;
  const float* g1 = gls + (bg * 2 + 1) * 128;
  for (int k = 0; k < 128; ++k) {
    float w = W2[(kc * 128 + k) * 1024 + n];
    acc0 += g0[k] * w;
    acc1 += g1[k] * w;
  }
  z2p[(kc * 16 + bg * 2) * 1024 + n] = acc0;
  z2p[(kc * 16 + bg * 2 + 1) * 1024 + n] = acc1;
}

// ---------------- k7: z recompute + FC2 reduce + residual + LayerNorm ----------------
__global__ __launch_bounds__(256) void k7_ln(const float* __restrict__ zp,
                                             const float* __restrict__ z2p,
                                             const float* __restrict__ b1,
                                             const float* __restrict__ b2,
                                             const float* __restrict__ ln_g,
                                             const float* __restrict__ ln_b,
                                             float* __restrict__ out) {
  __shared__ float r1[256], r2[256];
  int t = threadIdx.x, b = blockIdx.x;
  float4 v = *(const float4*)(b1 + t * 4);
  float4 bb2 = *(const float4*)(b2 + t * 4);
  v.x += bb2.x; v.y += bb2.y; v.z += bb2.z; v.w += bb2.w;
#pragma unroll
  for (int kc = 0; kc < 7; ++kc) {
    float4 p = *(const float4*)(zp + (kc * 16 + b) * 1024 + t * 4);
    v.x += p.x; v.y += p.y; v.z += p.z; v.w += p.w;
  }
#pragma unroll
  for (int kc = 0; kc < 8; ++kc) {
    float4 p = *(const float4*)(z2p + (kc * 16 + b) * 1024 + t * 4);
    v.x += p.x; v.y += p.y; v.z += p.z; v.w += p.w;
  }
  r1[t] = v.x + v.y + v.z + v.w;
  r2[t] = v.x * v.x + v.y * v.y + v.z * v.z + v.w * v.w;
  __syncthreads();
  for (int s = 128; s > 0; s >>= 1) {
    if (t < s) {
      r1[t] += r1[t + s];
      r2[t] += r2[t + s];
    }
    __syncthreads();
  }
  float mu = r1[0] * (1.f / 1024.f);
  float var = r2[0] * (1.f / 1024.f) - mu * mu;
  float rstd = rsqrtf(var + 1e-5f);
  float4 gg = *(const float4*)(ln_g + t * 4);
  float4 bb = *(const float4*)(ln_b + t * 4);
  float4 o;
  o.x = (v.x - mu) * rstd * gg.x + bb.x;
  o.y = (v.y - mu) * rstd * gg.y + bb.y;
  o.z = (v.z - mu) * rstd * gg.z + bb.z;
  o.w = (v.w - mu) * rstd * gg.w + bb.w;
  *(float4*)(out + b * 1024 + t * 4) = o;
}

extern "C" void kernel_launch(void* const* d_in, const int* in_sizes, int n_in,
                              void* d_out, int out_size, void* d_ws, size_t ws_size,
                              hipStream_t stream) {
  (void)in_sizes; (void)n_in; (void)out_size; (void)ws_size;
  const float* x       = (const float*)d_in[0];
  const float* gat_W   = (const float*)d_in[1];
  const float* att_src = (const float*)d_in[2];
  const float* att_dst = (const float*)d_in[3];
  const float* gat_b   = (const float*)d_in[4];
  const float* conv1_w = (const float*)d_in[5];
  const float* conv2_w = (const float*)d_in[11];
  const float* projc_w = (const float*)d_in[17];
  const float* projc_b = (const float*)d_in[18];
  const float* W1      = (const float*)d_in[19];
  const float* b1      = (const float*)d_in[20];
  const float* W2      = (const float*)d_in[21];
  const float* b2      = (const float*)d_in[22];
  const float* ln_g    = (const float*)d_in[23];
  const float* ln_b    = (const float*)d_in[24];
  float* ws  = (float*)d_ws;
  float* out = (float*)d_out;

  hipLaunchKernelGGL(k0_prep, dim3(993), dim3(256), 0, stream, gat_W, conv1_w,
                     (const float*)d_in[6], (const float*)d_in[7], (const float*)d_in[8],
                     (const float*)d_in[9], (const float*)d_in[10], (const float*)d_in[12],
                     (const float*)d_in[13], (const float*)d_in[14], (const float*)d_in[15],
                     (const float*)d_in[16], conv2_w, ws);
  hipLaunchKernelGGL(k1_mfma, dim3(256, 4), dim3(256), 0, stream, x,
                     (const unsigned short*)(ws + WS_WPT), gat_b, ws + WS_H, ws + WS_X1);
  hipLaunchKernelGGL(k1b_scores, dim3(256), dim3(256), 0, stream, ws + WS_H, att_src, att_dst,
                     ws + WS_AS, ws + WS_AD);
  hipLaunchKernelGGL(kP, dim3(1024), dim3(256), 0, stream, ws + WS_AS, ws + WS_AD, ws + WS_P);
  hipLaunchKernelGGL(kAttn, dim3(16, 4, 8), dim3(256), 0, stream, ws + WS_P, ws + WS_H,
                     ws + WS_AP);
  hipLaunchKernelGGL(kAttnRed, dim3(1024), dim3(256), 0, stream, ws + WS_AP, x, gat_b,
                     ws + WS_X1);
  hipLaunchKernelGGL(k3_conv, dim3(16, 128), dim3(320), 0, stream, ws + WS_X1,
                     (const unsigned short*)(ws + WS_W2P),
                     (const unsigned short*)(ws + WS_WEFB), ws, ws + WS_Y3P);
  hipLaunchKernelGGL(k4a_red, dim3(16, 7), dim3(256), 0, stream, ws + WS_Y3P, ws, ws + WS_Y4);
  hipLaunchKernelGGL(k4b_proj, dim3(16), dim3(256), 0, stream, ws + WS_Y4, projc_w, projc_b,
                     ws + WS_Y5);
  hipLaunchKernelGGL(k5_fc1, dim3(32, 7), dim3(256), 0, stream, ws + WS_Y5, W1, ws + WS_ZP);
  hipLaunchKernelGGL(k6_fc2, dim3(32, 8), dim3(256), 0, stream, ws + WS_ZP, b1, W2,
                     ws + WS_Z2P);
  hipLaunchKernelGGL(k7_ln, dim3(16), dim3(256), 0, stream, ws + WS_ZP, ws + WS_Z2P, b1, b2,
                     ln_g, ln_b, out);
}

// Round 11
// 235.365 us; speedup vs baseline: 1.4581x; 1.0435x over previous
//
#include <hip/hip_runtime.h>
#include <math.h>

typedef __attribute__((ext_vector_type(8))) short short8;
typedef __attribute__((ext_vector_type(4))) float f32x4;

__device__ __forceinline__ unsigned f2bf(float f) {
  unsigned u = __float_as_uint(f);
  return (u + 0x7FFFu + ((u >> 16) & 1u)) >> 16;
}
__device__ __forceinline__ unsigned pk2(float lo, float hi) {
  return f2bf(lo) | (f2bf(hi) << 16);
}

// ---------------- workspace layout (float offsets) ----------------
#define WS_X1    0                    // 16384*200
#define WS_W2P   3328000              // w2pre: 128*48*320 bf16 shorts
#define WS_AS    4966400              // 1024
#define WS_AD    4967424              // 1024
#define WS_WEFB  4968464              // weffB: 48*32 bf16
#define WS_S1    4969664              // 40
#define WS_SH1   4969704              // 40
#define WS_S2    4969744              // 40
#define WS_SH2   4969784              // 40
#define WS_H     4970496              // 1024*256 fp32
#define WS_P     5232640              // P bf16: 1024*1024 ushorts = 262144 floats
#define WS_HT    5494784              // hT bf16: 256*1024 ushorts = 131072 floats
#define WS_AP    6281216              // 8*1024*256 fp32 attention partials
#define WS_Y3P   WS_P                 // 16*128*1400 fp32 (overlays P/HT/AP; dead by k3)
#define WS_Y4    8378368              // 16*1400
#define WS_Y5    8400768              // 16*1400
#define WS_ZP    8455936              // 7*16*1024
#define WS_Z2P   8570624              // 8*16*1024
#define WS_WPT   8701696              // 256*224 bf16: gat_W^T zero-padded
// end 8,730,368 floats = 34.9 MB

// ---------------- k0: params + wpadT + weffB + w2pre ----------------
__global__ __launch_bounds__(256) void k0_prep(const float* __restrict__ gat_W,
                        const float* __restrict__ conv1_w, const float* __restrict__ conv1_b,
                        const float* __restrict__ bn1_g, const float* __restrict__ bn1_b,
                        const float* __restrict__ bn1_m, const float* __restrict__ bn1_v,
                        const float* __restrict__ conv2_b,
                        const float* __restrict__ bn2_g, const float* __restrict__ bn2_b,
                        const float* __restrict__ bn2_m, const float* __restrict__ bn2_v,
                        const float* __restrict__ w2,
                        float* __restrict__ ws) {
  int bx = blockIdx.x, t = threadIdx.x;
  if (bx < 224) {
    unsigned short* wpt = (unsigned short*)(ws + WS_WPT);
    int idx = bx * 256 + t;  // n*224 + k
    int n = idx / 224, k = idx % 224;
    float v = (n < 200 && k < 200) ? gat_W[k * 200 + n] : 0.f;
    wpt[idx] = (unsigned short)f2bf(v);
    return;
  }
  if (bx == 224) {
    if (t < 48) {
      unsigned short* wb = (unsigned short*)(ws + WS_WEFB);
      float wv[30];
      if (t < 40) {
        for (int j = 0; j < 30; ++j) {
          float s = 0.f;
          for (int tt = 0; tt < 5; ++tt) {
            int k = j - tt;
            if (k >= 0 && k < 26) s += conv1_w[t * 26 + k];
          }
          wv[j] = s * 0.2f;
        }
      }
      for (int k = 0; k < 32; ++k)
        wb[t * 32 + k] = (unsigned short)f2bf((t < 40 && k < 30) ? wv[k] : 0.f);
    }
    if (t < 40) {
      float s1 = bn1_g[t] * rsqrtf(bn1_v[t] + 1e-5f);
      ws[WS_S1 + t] = s1;
      ws[WS_SH1 + t] = bn1_b[t] + (conv1_b[t] - bn1_m[t]) * s1;
      float s2 = bn2_g[t] * rsqrtf(bn2_v[t] + 1e-5f);
      ws[WS_S2 + t] = s2;
      ws[WS_SH2 + t] = bn2_b[t] + (conv2_b[t] - bn2_m[t]) * s2;
    }
    return;
  }
  __shared__ unsigned short lds[2560];
  int q = bx - 225;
  int c8 = q / 6, o0 = (q % 6) * 8;
  unsigned short* w2p = (unsigned short*)(ws + WS_W2P);
#pragma unroll
  for (int i = 0; i < 10; ++i) {
    int e = i * 256 + t;
    int o = e / 320, rr = e % 320;
    int c = rr / 8, nl = rr % 8;
    int oa = o0 + o;
    float v = (oa < 40) ? w2[(oa * 40 + c) * 1024 + c8 * 8 + nl] : 0.f;
    lds[o * 320 + nl * 40 + c] = (unsigned short)f2bf(v);
  }
  __syncthreads();
  uint4* src = (uint4*)lds;
  uint4* dst = (uint4*)(w2p + (c8 * 48 + o0) * 320);
  for (int i = t; i < 320; i += 256) dst[i] = src[i];
}

// ---------------- k1: MFMA GEMM, 256 blocks, A packed once, 4 B-chunks in-loop ----
__global__ __launch_bounds__(256) void k1_mfma(const float* __restrict__ x,
                                               const unsigned short* __restrict__ wpt,
                                               const float* __restrict__ gat_b,
                                               float* __restrict__ h,
                                               unsigned short* __restrict__ hT,
                                               float* __restrict__ x1) {
  __shared__ unsigned short As[64 * 232];
  __shared__ unsigned short Bt[64 * 232];
  int t = threadIdx.x;
  int wave = t >> 6, lane = t & 63;
  int m16 = lane & 15, quad = lane >> 4;
  int row0 = blockIdx.x * 64;
  // pack A once: 64 rows x 224 cols bf16
  {
    int m = t >> 2, kq = (t & 3) * 8;
    const float* xr = x + (row0 + m) * 200;
#pragma unroll
    for (int s = 0; s < 7; ++s) {
      int kg = s * 32 + kq;
      uint4 pv;
      if (kg + 8 <= 200) {
        float4 a = *(const float4*)(xr + kg);
        float4 b = *(const float4*)(xr + kg + 4);
        pv.x = pk2(a.x, a.y); pv.y = pk2(a.z, a.w);
        pv.z = pk2(b.x, b.y); pv.w = pk2(b.z, b.w);
      } else {
        float e[8];
#pragma unroll
        for (int q = 0; q < 8; ++q) e[q] = (kg + q < 200) ? xr[kg + q] : 0.f;
        pv.x = pk2(e[0], e[1]); pv.y = pk2(e[2], e[3]);
        pv.z = pk2(e[4], e[5]); pv.w = pk2(e[6], e[7]);
      }
      *(uint4*)&As[m * 232 + kg] = pv;
    }
  }
  __syncthreads();
  for (int c = 0; c < 4; ++c) {
    int n0 = c * 64;
    for (int i = t; i < 1792; i += 256) {
      int row = i / 28, ch = i % 28;
      *(short8*)&Bt[row * 232 + ch * 8] = *(const short8*)&wpt[(n0 + row) * 224 + ch * 8];
    }
    __syncthreads();
    f32x4 acc[4];
#pragma unroll
    for (int nt = 0; nt < 4; ++nt) acc[nt] = (f32x4){0.f, 0.f, 0.f, 0.f};
#pragma unroll
    for (int s = 0; s < 7; ++s) {
      short8 af = *(const short8*)&As[(wave * 16 + m16) * 232 + s * 32 + quad * 8];
      int kb = s * 32 + quad * 8;
#pragma unroll
      for (int nt = 0; nt < 4; ++nt) {
        short8 bf = *(const short8*)&Bt[(nt * 16 + m16) * 232 + kb];
        acc[nt] = __builtin_amdgcn_mfma_f32_16x16x32_bf16(af, bf, acc[nt], 0, 0, 0);
      }
    }
    if (blockIdx.x < 16) {
#pragma unroll
      for (int nt = 0; nt < 4; ++nt) {
        int col = n0 + nt * 16 + m16;
#pragma unroll
        for (int r = 0; r < 4; ++r) {
          int row = row0 + wave * 16 + quad * 4 + r;
          float v = acc[nt][r];
          h[row * 256 + col] = v;
          hT[col * 1024 + row] = (unsigned short)f2bf(v);
        }
      }
    } else {
#pragma unroll
      for (int nt = 0; nt < 4; ++nt) {
        int col = n0 + nt * 16 + m16;
        if (col < 200) {
          float gb = gat_b[col];
#pragma unroll
          for (int r = 0; r < 4; ++r) {
            int row = row0 + wave * 16 + quad * 4 + r;
            x1[row * 200 + col] = x[row * 200 + col] + acc[nt][r] + gb;
          }
        }
      }
    }
    __syncthreads();
  }
}

// ---------------- k1b: attention scores — wave-per-row ----------------
__global__ __launch_bounds__(256) void k1b_scores(const float* __restrict__ h,
                                                  const float* __restrict__ att_src,
                                                  const float* __restrict__ att_dst,
                                                  float* __restrict__ as_,
                                                  float* __restrict__ ad_) {
  int t = threadIdx.x;
  int wave = t >> 6, lane = t & 63;
  int r = blockIdx.x * 4 + wave;
  float s = 0.f, d = 0.f;
  if (lane < 50) {
    float4 v = *(const float4*)(h + r * 256 + lane * 4);
    float4 a = *(const float4*)(att_src + lane * 4);
    float4 dd = *(const float4*)(att_dst + lane * 4);
    s = v.x * a.x + v.y * a.y + v.z * a.z + v.w * a.w;
    d = v.x * dd.x + v.y * dd.y + v.z * dd.z + v.w * dd.w;
  }
#pragma unroll
  for (int off = 32; off > 0; off >>= 1) {
    s += __shfl_down(s, off);
    d += __shfl_down(d, off);
  }
  if (lane == 0) {
    as_[r] = s;
    ad_[r] = d;
  }
}

// ---------------- kP: normalized softmax P -> bf16 ----------------
__global__ __launch_bounds__(256) void kP(const float* __restrict__ as_,
                                          const float* __restrict__ ad_,
                                          unsigned short* __restrict__ Pb) {
  __shared__ float rb[256];
  int t = threadIdx.x, i = blockIdx.x;
  float a0 = as_[t], a1 = as_[256 + t], a2 = as_[512 + t], a3 = as_[768 + t];
  rb[t] = fmaxf(fmaxf(a0, a1), fmaxf(a2, a3));
  __syncthreads();
  for (int st = 128; st > 0; st >>= 1) {
    if (t < st) rb[t] = fmaxf(rb[t], rb[t + st]);
    __syncthreads();
  }
  float maxs = rb[0];
  __syncthreads();
  float ad = ad_[i];
  float mv = maxs + ad;
  float M = mv >= 0.f ? mv : 0.2f * mv;
  float av[4] = {a0, a1, a2, a3};
  float p[4];
  float s = 0.f;
#pragma unroll
  for (int q = 0; q < 4; ++q) {
    float v = av[q] + ad;
    float l = v >= 0.f ? v : 0.2f * v;
    p[q] = __expf(l - M);
    s += p[q];
  }
  rb[t] = s;
  __syncthreads();
  for (int st = 128; st > 0; st >>= 1) {
    if (t < st) rb[t] += rb[t + st];
    __syncthreads();
  }
  float inv = 1.f / rb[0];
#pragma unroll
  for (int q = 0; q < 4; ++q)
    Pb[i * 1024 + q * 256 + t] = (unsigned short)f2bf(p[q] * inv);
}

// ---------------- kAttn: MFMA bf16 out0 = P @ h, LDS-free ----------------
// grid (16 i-tiles, 4 f-tiles, 8 K-chunks), block 256 (4 waves).
__global__ __launch_bounds__(256) void kAttn(const unsigned short* __restrict__ Pb,
                                             const unsigned short* __restrict__ hT,
                                             float* __restrict__ ap) {
  int t = threadIdx.x;
  int wave = t >> 6, lane = t & 63;
  int l15 = lane & 15, quad = lane >> 4;
  int i0 = blockIdx.x * 64, f0 = blockIdx.y * 64, j0 = blockIdx.z * 128;
  int arow = i0 + wave * 16 + l15;
  f32x4 acc[4];
#pragma unroll
  for (int nt = 0; nt < 4; ++nt) acc[nt] = (f32x4){0.f, 0.f, 0.f, 0.f};
#pragma unroll
  for (int ks = 0; ks < 4; ++ks) {
    int koff = j0 + ks * 32 + quad * 8;
    short8 a = *(const short8*)&Pb[arow * 1024 + koff];
#pragma unroll
    for (int nt = 0; nt < 4; ++nt) {
      short8 bf = *(const short8*)&hT[(f0 + nt * 16 + l15) * 1024 + koff];
      acc[nt] = __builtin_amdgcn_mfma_f32_16x16x32_bf16(a, bf, acc[nt], 0, 0, 0);
    }
  }
#pragma unroll
  for (int nt = 0; nt < 4; ++nt)
#pragma unroll
    for (int r = 0; r < 4; ++r) {
      int row = i0 + wave * 16 + quad * 4 + r;
      ap[(blockIdx.z * 1024 + row) * 256 + f0 + nt * 16 + l15] = acc[nt][r];
    }
}

// ---------------- kAttnRed ----------------
__global__ __launch_bounds__(256) void kAttnRed(const float* __restrict__ ap,
                                                const float* __restrict__ x,
                                                const float* __restrict__ gat_b,
                                                float* __restrict__ x1) {
  int t = threadIdx.x, r = blockIdx.x;
  if (t >= 200) return;
  float s = 0.f;
#pragma unroll
  for (int z = 0; z < 8; ++z) s += ap[(z * 1024 + r) * 256 + t];
  x1[r * 200 + t] = x[r * 200 + t] + s + gat_b[t];
}

// ---------------- k3 v10 (unchanged from R10): conv1 MFMA + conv2 MFMA ----------------
__global__ __launch_bounds__(320, 2) void k3_conv(const float* __restrict__ x1,
                                                  const unsigned short* __restrict__ w2pre,
                                                  const unsigned short* __restrict__ weffB,
                                                  const float* __restrict__ ws,
                                                  float* __restrict__ y3p) {
  __shared__ __align__(16) char smem[48448];
  float* xbp = (float*)smem;
  unsigned short* tA = (unsigned short*)(smem + 6400);
  unsigned short* t2 = (unsigned short*)(smem + 24832);
  int t = threadIdx.x;
  int b = blockIdx.x, nc = blockIdx.y;
  int n0 = nc * 8;
  int wave = t >> 6, lane = t & 63;
  int l15 = lane & 15, quad = lane >> 4;
  for (int i = t; i < 400; i += 320) {
    int nn = i / 50, q = i % 50;
    ((float4*)(xbp + nn * 200))[q] = ((const float4*)(x1 + (b * 1024 + n0 + nn) * 200))[q];
  }
  __syncthreads();
  if (t < 280) {
    int nn = t / 35, p = t % 35;
    const float* xr = xbp + nn * 200 + p * 5;
    uint pv[16];
#pragma unroll
    for (int kk = 0; kk < 15; ++kk) pv[kk] = pk2(xr[kk * 2], xr[kk * 2 + 1]);
    pv[15] = 0u;
    uint4* dst = (uint4*)(tA + t * 32);
    dst[0] = make_uint4(pv[0], pv[1], pv[2], pv[3]);
    dst[1] = make_uint4(pv[4], pv[5], pv[6], pv[7]);
    dst[2] = make_uint4(pv[8], pv[9], pv[10], pv[11]);
    dst[3] = make_uint4(pv[12], pv[13], pv[14], pv[15]);
  } else if (t < 288) {
    uint4 z = make_uint4(0u, 0u, 0u, 0u);
    uint4* dst = (uint4*)(tA + t * 32);
    dst[0] = z; dst[1] = z; dst[2] = z; dst[3] = z;
  }
  __syncthreads();
  {
    int mt0 = wave * 4;
    int nmt = wave < 4 ? 4 : 2;
    short8 bw[3];
    float s1v[3] = {0.f, 0.f, 0.f}, sh1v[3] = {0.f, 0.f, 0.f};
#pragma unroll
    for (int nt = 0; nt < 3; ++nt) {
      bw[nt] = *(const short8*)&weffB[(nt * 16 + l15) * 32 + quad * 8];
      int c = nt * 16 + l15;
      if (c < 40) {
        s1v[nt] = ws[WS_S1 + c];
        sh1v[nt] = ws[WS_SH1 + c];
      }
    }
    for (int mi = 0; mi < nmt; ++mi) {
      int mt = mt0 + mi;
      short8 a = *(const short8*)&tA[(mt * 16 + l15) * 32 + quad * 8];
#pragma unroll
      for (int nt = 0; nt < 3; ++nt) {
        int c = nt * 16 + l15;
        if (c >= 40) continue;
        f32x4 c4 = {0.f, 0.f, 0.f, 0.f};
        c4 = __builtin_amdgcn_mfma_f32_16x16x32_bf16(a, bw[nt], c4, 0, 0, 0);
#pragma unroll
        for (int r = 0; r < 4; ++r) {
          int m = mt * 16 + quad * 4 + r;
          if (m < 280) {
            float v = c4[r] * s1v[nt] + sh1v[nt];
            float e = v > 0.f ? v : __expf(v) - 1.f;
            int p = m % 35, nn = m / 35;
            t2[p * 328 + nn * 40 + c] = (unsigned short)f2bf(e);
          }
        }
      }
    }
  }
  __syncthreads();
  f32x4 acc[3][3];
#pragma unroll
  for (int mt = 0; mt < 3; ++mt)
#pragma unroll
    for (int nt = 0; nt < 3; ++nt) acc[mt][nt] = (f32x4){0.f, 0.f, 0.f, 0.f};
  const unsigned short* bbase = w2pre + nc * 48 * 320;
#pragma unroll
  for (int ks = 0; ks < 2; ++ks) {
    int koff = wave * 64 + ks * 32 + quad * 8;
    short8 a[3], bb[3];
#pragma unroll
    for (int mt = 0; mt < 3; ++mt) {
      int row = mt * 16 + l15;
      row = row > 35 ? 35 : row;
      a[mt] = *(const short8*)&t2[row * 328 + koff];
    }
#pragma unroll
    for (int nt = 0; nt < 3; ++nt)
      bb[nt] = *(const short8*)&bbase[(nt * 16 + l15) * 320 + koff];
#pragma unroll
    for (int mt = 0; mt < 3; ++mt)
#pragma unroll
      for (int nt = 0; nt < 3; ++nt)
        acc[mt][nt] = __builtin_amdgcn_mfma_f32_16x16x32_bf16(a[mt], bb[nt], acc[mt][nt], 0, 0, 0);
  }
  __syncthreads();
  float* red0 = (float*)smem;
  float* red1 = red0 + 48 * 49;
  if (wave < 2) {
    float* r = wave ? red1 : red0;
#pragma unroll
    for (int mt = 0; mt < 3; ++mt)
#pragma unroll
      for (int nt = 0; nt < 3; ++nt)
#pragma unroll
        for (int q = 0; q < 4; ++q)
          r[(mt * 16 + quad * 4 + q) * 49 + nt * 16 + l15] = acc[mt][nt][q];
  }
  __syncthreads();
  if (wave == 2 || wave == 3) {
    float* r = (wave == 3) ? red1 : red0;
#pragma unroll
    for (int mt = 0; mt < 3; ++mt)
#pragma unroll
      for (int nt = 0; nt < 3; ++nt)
#pragma unroll
        for (int q = 0; q < 4; ++q)
          r[(mt * 16 + quad * 4 + q) * 49 + nt * 16 + l15] += acc[mt][nt][q];
  }
  __syncthreads();
  if (wave == 4) {
#pragma unroll
    for (int mt = 0; mt < 3; ++mt)
#pragma unroll
      for (int nt = 0; nt < 3; ++nt)
#pragma unroll
        for (int q = 0; q < 4; ++q)
          red0[(mt * 16 + quad * 4 + q) * 49 + nt * 16 + l15] += acc[mt][nt][q];
  }
  __syncthreads();
  float* dst = y3p + (b * 128 + nc) * 1400;
  for (int idx = t; idx < 1400; idx += 320) {
    int o = idx / 35, p = idx % 35;
    dst[idx] = red0[p * 49 + o] + red1[p * 49 + o];
  }
}

// ---------------- k4a: reduce 128 partials + bn2 + elu -> y4 ----------------
__global__ __launch_bounds__(256) void k4a_red(const float* __restrict__ y3p,
                                               const float* __restrict__ ws,
                                               float* __restrict__ y4) {
  int t = threadIdx.x;
  if (t >= 200) return;
  int b = blockIdx.x;
  int idx = blockIdx.y * 200 + t;
  float s = 0.f;
#pragma unroll 4
  for (int q = 0; q < 128; ++q) s += y3p[(b * 128 + q) * 1400 + idx];
  int o = idx / 35;
  float v = s * ws[WS_S2 + o] + ws[WS_SH2 + o];
  y4[b * 1400 + idx] = v > 0.f ? v : __expf(v) - 1.f;
}

// ---------------- k4b: projc + rearrange -> y5 ----------------
__global__ __launch_bounds__(256) void k4b_proj(const float* __restrict__ y4,
                                                const float* __restrict__ projc_w,
                                                const float* __restrict__ projc_b,
                                                float* __restrict__ y5) {
  __shared__ __align__(16) float tls[1400];
  int t = threadIdx.x, b = blockIdx.x;
  for (int i = t; i < 350; i += 256)
    ((float4*)tls)[i] = ((const float4*)(y4 + b * 1400))[i];
  __syncthreads();
  for (int idx = t; idx < 1400; idx += 256) {
    int p = idx / 40, e = idx % 40;
    float acc = projc_b[e];
    for (int o = 0; o < 40; ++o) acc += tls[o * 35 + p] * projc_w[e * 40 + o];
    y5[b * 1400 + idx] = acc;
  }
}

// ---------------- k5: split-K FC1 partials ----------------
__global__ __launch_bounds__(256) void k5_fc1(const float* __restrict__ y5,
                                              const float* __restrict__ W1,
                                              float* __restrict__ zp) {
  __shared__ __align__(16) float yls[3200];
  int t = threadIdx.x;
  int nc = blockIdx.x, kc = blockIdx.y;  // (32, 7)
  for (int i = t; i < 800; i += 256) {
    int bb = i / 50, q = i % 50;
    ((float4*)yls)[bb * 50 + q] = *(const float4*)(y5 + bb * 1400 + kc * 200 + q * 4);
  }
  __syncthreads();
  int nl = t & 31, bg = t >> 5;
  int n = nc * 32 + nl;
  float acc0 = 0.f, acc1 = 0.f;
  const float* y0 = yls + (bg * 2) * 200;
  const float* y1 = yls + (bg * 2 + 1) * 200;
  for (int k = 0; k < 200; ++k) {
    float w = W1[(kc * 200 + k) * 1024 + n];
    acc0 += y0[k] * w;
    acc1 += y1[k] * w;
  }
  zp[(kc * 16 + bg * 2) * 1024 + n] = acc0;
  zp[(kc * 16 + bg * 2 + 1) * 1024 + n] = acc1;
}

// ---------------- k6: split-K FC2 partials, gelu(z) on the fly ----------------
__global__ __launch_bounds__(256) void k6_fc2(const float* __restrict__ zp,
                                              const float* __restrict__ b1,
                                              const float* __restrict__ W2,
                                              float* __restrict__ z2p) {
  __shared__ __align__(16) float gls[2048];
  int t = threadIdx.x;
  int nc = blockIdx.x, kc = blockIdx.y;  // (32, 8)
  for (int i = t; i < 2048; i += 256) {
    int bb = i >> 7, kk = i & 127;
    int np = kc * 128 + kk;
    float s = b1[np];
#pragma unroll
    for (int j = 0; j < 7; ++j) s += zp[(j * 16 + bb) * 1024 + np];
    gls[i] = 0.5f * s * (1.f + erff(s * 0.70710678f));
  }
  __syncthreads();
  int nl = t & 31, bg = t >> 5;
  int n = nc * 32 + nl;
  float acc0 = 0.f, acc1 = 0.f;
  const float* g0 = gls + (bg * 2) * 128;
  const float* g1 = gls + (bg * 2 + 1) * 128;
  for (int k = 0; k < 128; ++k) {
    float w = W2[(kc * 128 + k) * 1024 + n];
    acc0 += g0[k] * w;
    acc1 += g1[k] * w;
  }
  z2p[(kc * 16 + bg * 2) * 1024 + n] = acc0;
  z2p[(kc * 16 + bg * 2 + 1) * 1024 + n] = acc1;
}

// ---------------- k7: z recompute + FC2 reduce + residual + LayerNorm ----------------
__global__ __launch_bounds__(256) void k7_ln(const float* __restrict__ zp,
                                             const float* __restrict__ z2p,
                                             const float* __restrict__ b1,
                                             const float* __restrict__ b2,
                                             const float* __restrict__ ln_g,
                                             const float* __restrict__ ln_b,
                                             float* __restrict__ out) {
  __shared__ float r1[256], r2[256];
  int t = threadIdx.x, b = blockIdx.x;
  float4 v = *(const float4*)(b1 + t * 4);
  float4 bb2 = *(const float4*)(b2 + t * 4);
  v.x += bb2.x; v.y += bb2.y; v.z += bb2.z; v.w += bb2.w;
#pragma unroll
  for (int kc = 0; kc < 7; ++kc) {
    float4 p = *(const float4*)(zp + (kc * 16 + b) * 1024 + t * 4);
    v.x += p.x; v.y += p.y; v.z += p.z; v.w += p.w;
  }
#pragma unroll
  for (int kc = 0; kc < 8; ++kc) {
    float4 p = *(const float4*)(z2p + (kc * 16 + b) * 1024 + t * 4);
    v.x += p.x; v.y += p.y; v.z += p.z; v.w += p.w;
  }
  r1[t] = v.x + v.y + v.z + v.w;
  r2[t] = v.x * v.x + v.y * v.y + v.z * v.z + v.w * v.w;
  __syncthreads();
  for (int s = 128; s > 0; s >>= 1) {
    if (t < s) {
      r1[t] += r1[t + s];
      r2[t] += r2[t + s];
    }
    __syncthreads();
  }
  float mu = r1[0] * (1.f / 1024.f);
  float var = r2[0] * (1.f / 1024.f) - mu * mu;
  float rstd = rsqrtf(var + 1e-5f);
  float4 gg = *(const float4*)(ln_g + t * 4);
  float4 bb = *(const float4*)(ln_b + t * 4);
  float4 o;
  o.x = (v.x - mu) * rstd * gg.x + bb.x;
  o.y = (v.y - mu) * rstd * gg.y + bb.y;
  o.z = (v.z - mu) * rstd * gg.z + bb.z;
  o.w = (v.w - mu) * rstd * gg.w + bb.w;
  *(float4*)(out + b * 1024 + t * 4) = o;
}

extern "C" void kernel_launch(void* const* d_in, const int* in_sizes, int n_in,
                              void* d_out, int out_size, void* d_ws, size_t ws_size,
                              hipStream_t stream) {
  (void)in_sizes; (void)n_in; (void)out_size; (void)ws_size;
  const float* x       = (const float*)d_in[0];
  const float* gat_W   = (const float*)d_in[1];
  const float* att_src = (const float*)d_in[2];
  const float* att_dst = (const float*)d_in[3];
  const float* gat_b   = (const float*)d_in[4];
  const float* conv1_w = (const float*)d_in[5];
  const float* conv2_w = (const float*)d_in[11];
  const float* projc_w = (const float*)d_in[17];
  const float* projc_b = (const float*)d_in[18];
  const float* W1      = (const float*)d_in[19];
  const float* b1      = (const float*)d_in[20];
  const float* W2      = (const float*)d_in[21];
  const float* b2      = (const float*)d_in[22];
  const float* ln_g    = (const float*)d_in[23];
  const float* ln_b    = (const float*)d_in[24];
  float* ws  = (float*)d_ws;
  float* out = (float*)d_out;

  hipLaunchKernelGGL(k0_prep, dim3(993), dim3(256), 0, stream, gat_W, conv1_w,
                     (const float*)d_in[6], (const float*)d_in[7], (const float*)d_in[8],
                     (const float*)d_in[9], (const float*)d_in[10], (const float*)d_in[12],
                     (const float*)d_in[13], (const float*)d_in[14], (const float*)d_in[15],
                     (const float*)d_in[16], conv2_w, ws);
  hipLaunchKernelGGL(k1_mfma, dim3(256), dim3(256), 0, stream, x,
                     (const unsigned short*)(ws + WS_WPT), gat_b, ws + WS_H,
                     (unsigned short*)(ws + WS_HT), ws + WS_X1);
  hipLaunchKernelGGL(k1b_scores, dim3(256), dim3(256), 0, stream, ws + WS_H, att_src, att_dst,
                     ws + WS_AS, ws + WS_AD);
  hipLaunchKernelGGL(kP, dim3(1024), dim3(256), 0, stream, ws + WS_AS, ws + WS_AD,
                     (unsigned short*)(ws + WS_P));
  hipLaunchKernelGGL(kAttn, dim3(16, 4, 8), dim3(256), 0, stream,
                     (const unsigned short*)(ws + WS_P),
                     (const unsigned short*)(ws + WS_HT), ws + WS_AP);
  hipLaunchKernelGGL(kAttnRed, dim3(1024), dim3(256), 0, stream, ws + WS_AP, x, gat_b,
                     ws + WS_X1);
  hipLaunchKernelGGL(k3_conv, dim3(16, 128), dim3(320), 0, stream, ws + WS_X1,
                     (const unsigned short*)(ws + WS_W2P),
                     (const unsigned short*)(ws + WS_WEFB), ws, ws + WS_Y3P);
  hipLaunchKernelGGL(k4a_red, dim3(16, 7), dim3(256), 0, stream, ws + WS_Y3P, ws, ws + WS_Y4);
  hipLaunchKernelGGL(k4b_proj, dim3(16), dim3(256), 0, stream, ws + WS_Y4, projc_w, projc_b,
                     ws + WS_Y5);
  hipLaunchKernelGGL(k5_fc1, dim3(32, 7), dim3(256), 0, stream, ws + WS_Y5, W1, ws + WS_ZP);
  hipLaunchKernelGGL(k6_fc2, dim3(32, 8), dim3(256), 0, stream, ws + WS_ZP, b1, W2,
                     ws + WS_Z2P);
  hipLaunchKernelGGL(k7_ln, dim3(16), dim3(256), 0, stream, ws + WS_ZP, ws + WS_Z2P, b1, b2,
                     ln_g, ln_b, out);
}